// Round 6
// baseline (467.812 us; speedup 1.0000x reference)
//
#include <hip/hip_runtime.h>
#include <hip/hip_bf16.h>

// EPiC network, round 17: r16 base (passing, 447us) + two targeted fixes.
// Counter evidence r16: proj Occupancy 8.3% (80% of its 62us is the single-WG
// winner tail on cold HBM weights); epic_local 61.6us with ~20us LDS-read floor
// (weights re-read per group) + ~20us tail gap (Occ 30% vs 50% cap).
// Fix A: tail-weight PREFETCH into shared L3/L2 by 16 spread WGs during the
//   local phase (asm-volatile DCE guard). Tails become cache-hit.
// Fix B: epic_local -> 512 thr / 8 waves, each wave 4 groups as 2 PAIRS
//   sharing all weight-frag ds_reads (LDS traffic halved, MFMA ILP 4 chains).
//   256-reg budget (2 waves/SIMD), ~190 regs, no spill. All index formulas
//   verbatim from verified r14/r16 epic_pass.
// epic_last, prep, proj local phase, winner-tail algorithm: unchanged (verified).

typedef __attribute__((ext_vector_type(8))) short short8;
typedef __attribute__((ext_vector_type(4))) float f32x4;

#define B_ 16
#define N_ 8192
#define DC_ 16
#define H_ 128
#define G_ 10
#define NB_ 6
#define NEG_ 0.01f

__device__ __forceinline__ float lrelu(float x) { return x > 0.f ? x : NEG_ * x; }

__device__ __forceinline__ unsigned short f2bf(float x) {
  union { float f; unsigned u; } v; v.f = x;
  return (unsigned short)((v.u + 0x7fffu + ((v.u >> 16) & 1u)) >> 16);  // RNE
}
__device__ __forceinline__ float bf2f(unsigned short u) {
  union { unsigned u; float f; } v; v.u = ((unsigned)u) << 16; return v.f;
}
// truncating hi (1 op) + RNE lo of residual; pair represents x to ~2^-17
__device__ __forceinline__ void split_bf(float x, unsigned short& h, unsigned short& l) {
  union { float f; unsigned u; } v; v.f = x;
  unsigned hu = v.u & 0xffff0000u;
  h = (unsigned short)(hu >> 16);
  union { unsigned u; float f; } hv; hv.u = hu;
  l = f2bf(x - hv.f);
}

__device__ __forceinline__ f32x4 mfma16(short8 a, short8 b, f32x4 c) {
  return __builtin_amdgcn_mfma_f32_16x16x32_bf16(a, b, c, 0, 0, 0);
}

__device__ __forceinline__ void make_frags(f32x4 v0, f32x4 v1, short8& bh, short8& bl) {
  unsigned short h, l;
#pragma unroll
  for (int j = 0; j < 4; ++j) {
    split_bf(v0[j], h, l);
    bh[j] = (short)h; bl[j] = (short)l;
  }
#pragma unroll
  for (int j = 0; j < 4; ++j) {
    split_bf(v1[j], h, l);
    bh[4 + j] = (short)h; bl[4 + j] = (short)l;
  }
}

// async 16B-per-lane global -> LDS copy (lane-contiguous DMA)
__device__ __forceinline__ void async_cp16(const void* g, void* l) {
  __builtin_amdgcn_global_load_lds(
      (const __attribute__((address_space(1))) void*)g,
      (__attribute__((address_space(3))) void*)l, 16, 0, 0);
}

// agent-scope write-through publication (no L2 flush)
__device__ __forceinline__ void agent_store(float* p, float v) {
  __hip_atomic_store(p, v, __ATOMIC_RELAXED, __HIP_MEMORY_SCOPE_AGENT);
}
__device__ __forceinline__ float agent_load(const float* p) {
  return __hip_atomic_load(p, __ATOMIC_RELAXED, __HIP_MEMORY_SCOPE_AGENT);
}

// ---- common tail: pool(NS slots) -> h_g -> xg residual -> folded gbias ----
// Works for blockDim 256/512/1024: compute guarded, barriers unconditional.
template <int NS>
__device__ void epic_global_tail(
    int b, int tid, const float* __restrict__ pP, float cnt,
    const float* __restrict__ xg_cur, float* __restrict__ xg_next,
    const float* __restrict__ context,
    const float* __restrict__ g1w_n, const float* __restrict__ g1b_n,
    const float* __restrict__ g2w_n, const float* __restrict__ g2b_n,
    const float* __restrict__ l1w_n, const float* __restrict__ l1b_n,
    float* __restrict__ gbias_out, float* shx) {
  if (tid < 256) {
    const int f = tid & 127, kh = tid >> 7;
    const float* pr = pP + ((size_t)b * NS + kh * (NS / 2)) * 128 + f;
    float s = 0.f;
#pragma unroll 8
    for (int w = 0; w < NS / 2; ++w) s += agent_load(pr + w * 128);
    shx[tid] = s;
  }
  __syncthreads();
  if (tid < 128) {
    float s = shx[tid] + shx[tid + 128];
    shx[384 + tid] = s;
    shx[256 + tid] = s / cnt;
  }
  if (tid < G_) shx[512 + tid] = xg_cur[tid];
  if (tid >= 32 && tid < 32 + DC_) shx[522 + tid - 32] = context[b * DC_ + tid - 32];
  __syncthreads();
  if (tid < 256) {
    const int f = tid & 127, kh = tid >> 7;
    const float* wr = g1w_n + (size_t)f * 282 + kh * 142;
    const float* vp = shx + 256 + kh * 142;
    const int n2 = kh ? 70 : 71;
    float a = 0.f;
#pragma unroll 8
    for (int j = 0; j < n2; ++j) {
      float2 w2 = *(const float2*)(wr + 2 * j);
      a += w2.x * vp[2 * j] + w2.y * vp[2 * j + 1];
    }
    shx[tid] = a;  // writes 0..255; reads were 256..539 (disjoint)
  }
  __syncthreads();
  if (tid < 128) shx[544 + tid] = lrelu(shx[tid] + shx[tid + 128] + g1b_n[tid]);
  __syncthreads();
  if (tid < G_) {
    const float* wr = g2w_n + tid * 128;
    float a = g2b_n[tid] + shx[512 + tid];
#pragma unroll 8
    for (int j = 0; j < 32; ++j) {
      float4 w4 = *(const float4*)(wr + 4 * j);
      a += w4.x * shx[544 + 4 * j] + w4.y * shx[544 + 4 * j + 1] +
           w4.z * shx[544 + 4 * j + 2] + w4.w * shx[544 + 4 * j + 3];
    }
    float v = lrelu(a);
    shx[672 + tid] = v;
    xg_next[tid] = v;
  }
  __syncthreads();
  if (tid < 128) {
    const float* wr = l1w_n + tid * 154;
    float a = l1b_n[tid];
#pragma unroll
    for (int j = 0; j < G_; ++j) a += wr[128 + j] * shx[672 + j];
#pragma unroll
    for (int j = 0; j < DC_; ++j) a += wr[138 + j] * shx[522 + j];
    gbias_out[tid] = a;
  }
}

// ---------------- weight prep: split + frag-order swizzle ----------------
__global__ __launch_bounds__(256) void prep_weights(
    const float* __restrict__ l1w, const float* __restrict__ l2w,
    unsigned short* __restrict__ w1h, unsigned short* __restrict__ w1l,
    unsigned short* __restrict__ w2h, unsigned short* __restrict__ w2l,
    unsigned int* __restrict__ counters) {
  int idx = blockIdx.x * 256 + threadIdx.x;
  const int total = NB_ * H_ * H_;
  if (idx < 112) counters[idx] = 0u;
  if (idx < total) {
    int i = idx / (H_ * H_), rem = idx % (H_ * H_);
    int F = rem / H_, k = rem % H_;
    int ks = k >> 5, c = k & 31;
    int mt2 = F >> 4, r2 = F & 15;
    int mt1 = ((F >> 5) << 1) | ((F >> 2) & 1);
    int r1 = (((F >> 3) & 3) << 2) | (F & 3);
    int off1 = i * 16384 + (mt1 * 4 + ks) * 512 + ((c >> 3) * 16 + r1) * 8 + (c & 7);
    int off2 = i * 16384 + (mt2 * 4 + ks) * 512 + ((c >> 3) * 16 + r2) * 8 + (c & 7);
    unsigned short h, l;
    split_bf(l1w[(i * H_ + F) * 154 + k], h, l);
    w1h[off1] = h; w1l[off1] = l;
    split_bf(l2w[(i * H_ + F) * H_ + k], h, l);
    w2h[off2] = h; w2l[off2] = l;
  }
}

// ---------------- projection local (writes 16-pt-group xl) + proj/blk0 tail ----
__global__ __launch_bounds__(256, 2) void proj_local_kernel(
    const float* __restrict__ xloc, const float* __restrict__ maskp,
    const float* __restrict__ plw, const float* __restrict__ plb,
    float* __restrict__ xlf, float* __restrict__ pP,
    float* __restrict__ cntp, float* __restrict__ cnt_g,
    unsigned int* __restrict__ counters,
    const float* __restrict__ context,
    const float* __restrict__ g0w, const float* __restrict__ g0b,
    const float* __restrict__ g1pw, const float* __restrict__ g1pb,
    const float* __restrict__ g2pw, const float* __restrict__ g2pb,
    float* __restrict__ xg_g,
    const float* __restrict__ g1w0, const float* __restrict__ g1b0,
    const float* __restrict__ g2w0, const float* __restrict__ g2b0,
    const float* __restrict__ l1w0, const float* __restrict__ l1b0,
    float* __restrict__ gbias_g) {
  __shared__ float wq[H_][4];
  __shared__ float wsum[512];
  __shared__ float cw[4];
  __shared__ float shx[768];
  __shared__ int winflag;
  const int tid = threadIdx.x, bid = blockIdx.x;
  const int wv = tid >> 6, lane = tid & 63;
  const int q = lane >> 4, n16 = lane & 15;
  const int b = bid >> 6;

  // ---- Fix A: prefetch tail weights into L3/L2 (32 spread WGs) ----
  float pfacc = 0.f;
  if ((bid & 31) == 0) {
    const int ch = bid >> 5;           // 0..31
    const int t0 = ch * 256 + tid, STR = 32 * 256;
    const float4* p;
    p = (const float4*)g0w;  for (int i = t0; i < 8704; i += STR) pfacc += p[i].x;
    p = (const float4*)g1pw; for (int i = t0; i < 4096; i += STR) pfacc += p[i].x;
    p = (const float4*)g1w0; for (int i = t0; i < 9024; i += STR) pfacc += p[i].x;
    p = (const float4*)l1w0; for (int i = t0; i < 4928; i += STR) pfacc += p[i].x;
    if (t0 < 320) pfacc += ((const float4*)g2pw)[t0].x + ((const float4*)g2w0)[t0].x;
  }

  if (tid < H_) {
    wq[tid][0] = plw[tid * 3 + 0];
    wq[tid][1] = plw[tid * 3 + 1];
    wq[tid][2] = plw[tid * 3 + 2];
    wq[tid][3] = plb[tid];
  }
  __syncthreads();
  const int t = bid * 4 + wv;            // 32-pt tile index
  const int p0 = t * 32;
  const int pa = p0 + n16, pb = p0 + 16 + n16;
  const float xa0 = xloc[pa * 3], xa1 = xloc[pa * 3 + 1], xa2 = xloc[pa * 3 + 2];
  const float xb0 = xloc[pb * 3], xb1 = xloc[pb * 3 + 1], xb2 = xloc[pb * 3 + 2];
  const float m0 = maskp[pa], m1 = maskp[pb];
  float* ga = xlf + (size_t)(2 * t) * 2048;
  float* gb = ga + 2048;
#pragma unroll
  for (int ms = 0; ms < 8; ++ms) {
    f32x4 v0, v1;
#pragma unroll
    for (int r = 0; r < 4; ++r) {
      const int F = ms * 16 + q * 4 + r;
      float4 w4 = *(const float4*)wq[F];
      v0[r] = lrelu(w4.x * xa0 + w4.y * xa1 + w4.z * xa2 + w4.w) * m0;
      v1[r] = lrelu(w4.x * xb0 + w4.y * xb1 + w4.z * xb2 + w4.w) * m1;
    }
    *(f32x4*)(ga + ms * 256 + (q * 16 + n16) * 4) = v0;
    *(f32x4*)(gb + ms * 256 + (q * 16 + n16) * 4) = v1;
    f32x4 s = v0 + v1;
#pragma unroll
    for (int r = 0; r < 4; ++r) {
      float sv = s[r];
      sv += __shfl_xor(sv, 1, 64);
      sv += __shfl_xor(sv, 2, 64);
      sv += __shfl_xor(sv, 4, 64);
      sv += __shfl_xor(sv, 8, 64);
      s[r] = sv;
    }
    if (n16 == 0) *(f32x4*)&wsum[wv * 128 + ms * 16 + q * 4] = s;
  }
  {
    float c = (q == 0) ? (m0 + m1) : 0.f;
    c += __shfl_xor(c, 1, 64);
    c += __shfl_xor(c, 2, 64);
    c += __shfl_xor(c, 4, 64);
    c += __shfl_xor(c, 8, 64);
    if (lane == 0) cw[wv] = c;
  }
  __syncthreads();
  // two 64-pt slots per WG -> 128 slots per batch
  if (tid < 128) {
    agent_store(&pP[(size_t)(2 * bid) * 128 + tid], wsum[tid] + wsum[128 + tid]);
    agent_store(&pP[(size_t)(2 * bid + 1) * 128 + tid], wsum[256 + tid] + wsum[384 + tid]);
  }
  if (tid == 0) agent_store(&cntp[bid], cw[0] + cw[1] + cw[2] + cw[3]);
  asm volatile("" :: "v"(pfacc));  // keep prefetch loads live (rule #17)

  // ---- winner tail: proj global path + block-0 global path ----
  __syncthreads();
  if (tid == 0) winflag = (atomicAdd(&counters[b], 1u) == 63u) ? 1 : 0;
  __syncthreads();
  if (!winflag) return;
  if (tid < 64) shx[688 + tid] = agent_load(&cntp[b * 64 + tid]);
  __syncthreads();
  if (tid == 0) {
    float c = 0.f;
#pragma unroll
    for (int w = 0; w < 64; ++w) c += shx[688 + w];
    shx[752] = c;
    cnt_g[b] = c;
  }
  __syncthreads();
  const float cnt = shx[752];
  {
    const int f = tid & 127, kh = tid >> 7;
    const float* pr = pP + ((size_t)b * 128 + kh * 64) * 128 + f;
    float s = 0.f;
#pragma unroll 8
    for (int w = 0; w < 64; ++w) s += agent_load(pr + w * 128);
    shx[tid] = s;
  }
  __syncthreads();
  if (tid < 128) {
    float s = shx[tid] + shx[tid + 128];
    shx[384 + tid] = s;
    shx[256 + tid] = s / cnt;
  }
  if (tid < DC_) shx[512 + tid] = context[b * DC_ + tid];
  __syncthreads();
  {
    const int f = tid & 127, kh = tid >> 7;
    const float* wr = g0w + (size_t)f * 272 + kh * 136;
    const float* vp = shx + 256 + kh * 136;
    float a = 0.f;
#pragma unroll 8
    for (int j = 0; j < 34; ++j) {
      float4 w4 = *(const float4*)(wr + 4 * j);
      a += w4.x * vp[4 * j] + w4.y * vp[4 * j + 1] + w4.z * vp[4 * j + 2] + w4.w * vp[4 * j + 3];
    }
    __syncthreads();
    shx[tid] = a;
  }
  __syncthreads();
  if (tid < 128) shx[544 + tid] = lrelu(shx[tid] + shx[tid + 128] + g0b[tid]);
  __syncthreads();
  {
    const int f = tid & 127, kh = tid >> 7;
    const float* wr = g1pw + (size_t)f * 128 + kh * 64;
    const float* vp = shx + 544 + kh * 64;
    float a = 0.f;
#pragma unroll 8
    for (int j = 0; j < 16; ++j) {
      float4 w4 = *(const float4*)(wr + 4 * j);
      a += w4.x * vp[4 * j] + w4.y * vp[4 * j + 1] + w4.z * vp[4 * j + 2] + w4.w * vp[4 * j + 3];
    }
    __syncthreads();
    shx[tid] = a;
  }
  __syncthreads();
  if (tid < 128) shx[544 + tid] = lrelu(shx[tid] + shx[tid + 128] + g1pb[tid]);
  __syncthreads();
  if (tid < G_) {
    const float* wr = g2pw + tid * 128;
    float a = g2pb[tid];
#pragma unroll 8
    for (int j = 0; j < 32; ++j) {
      float4 w4 = *(const float4*)(wr + 4 * j);
      a += w4.x * shx[544 + 4 * j] + w4.y * shx[544 + 4 * j + 1] +
           w4.z * shx[544 + 4 * j + 2] + w4.w * shx[544 + 4 * j + 3];
    }
    xg_g[(0 * 16 + b) * 16 + tid] = lrelu(a);
  }
  __syncthreads();
  epic_global_tail<128>(b, tid, pP, cnt,
                        xg_g + (0 * 16 + b) * 16, xg_g + (1 * 16 + b) * 16, context,
                        g1w0, g1b0, g2w0, g2b0, l1w0, l1b0,
                        gbias_g + (size_t)(0 * 16 + b) * 128, shx);
}

// ---- per-group x B-frag load (B-layout, verified) ----
__device__ __forceinline__ void load_frags(const float* base_g, int q, int n16,
                                           short8* xbh, short8* xbl) {
#pragma unroll
  for (int ks = 0; ks < 4; ++ks) {
    const float* pb = base_g + (2 * ks + (q >> 1)) * 256 + ((q & 1) * 32 + n16) * 4;
    f32x4 v0 = *(const f32x4*)pb;
    f32x4 v1 = *(const f32x4*)(pb + 64);
    make_frags(v0, v1, xbh[ks], xbl[ks]);
  }
}

// ---- Fix B: PAIR pass — two groups share every weight-frag ds_read.
// All offset formulas verbatim from verified r14/r16 epic_pass.
__device__ __forceinline__ void pair_pass2(
    int g0i, int q, int n16, int lane16,
    const short8 (&xh)[2][4], const short8 (&xl)[2][4],
    const unsigned short* w1h_l, const unsigned short* w1l_l,
    const unsigned short* w2h_l, const unsigned short* w2l_l,
    const float* gbias_s, const float* l2b_s,
    float* wsum_row, float* __restrict__ xlf, const float* __restrict__ maskp) {
  f32x4 acc2[2][8];
#pragma unroll
  for (int g = 0; g < 2; ++g)
#pragma unroll
    for (int ms = 0; ms < 8; ++ms) acc2[g][ms] = (f32x4){0.f, 0.f, 0.f, 0.f};

#pragma unroll 1
  for (int ko = 0; ko < 4; ++ko) {
    // ---- GEMM1: shared w1 frags; 4 independent chains (g x t) ----
    f32x4 acc[2][2];
#pragma unroll
    for (int g = 0; g < 2; ++g)
#pragma unroll
      for (int t = 0; t < 2; ++t) acc[g][t] = (f32x4){0.f, 0.f, 0.f, 0.f};
#pragma unroll
    for (int t = 0; t < 2; ++t) {
#pragma unroll
      for (int kc = 0; kc < 2; ++kc) {
        short8 a1h[2], a1l[2];
#pragma unroll
        for (int u = 0; u < 2; ++u) {
          const int off = ((ko * 2 + t) * 4 + kc * 2 + u) * 512 + lane16;
          a1h[u] = *(const short8*)(w1h_l + off);
          a1l[u] = *(const short8*)(w1l_l + off);
        }
#pragma unroll
        for (int u = 0; u < 2; ++u) {
          const int ks = kc * 2 + u;
          acc[0][t] = mfma16(a1h[u], xh[0][ks], acc[0][t]);
          acc[0][t] = mfma16(a1l[u], xh[0][ks], acc[0][t]);
          acc[0][t] = mfma16(a1h[u], xl[0][ks], acc[0][t]);
          acc[1][t] = mfma16(a1h[u], xh[1][ks], acc[1][t]);
          acc[1][t] = mfma16(a1l[u], xh[1][ks], acc[1][t]);
          acc[1][t] = mfma16(a1h[u], xl[1][ks], acc[1][t]);
        }
      }
    }
    // ---- lane-local h -> GEMM2 B-frags ----
    f32x4 gb0 = *(const f32x4*)&gbias_s[ko * 32 + q * 8];
    f32x4 gb1 = *(const f32x4*)&gbias_s[ko * 32 + q * 8 + 4];
    short8 b2h[2], b2l[2];
#pragma unroll
    for (int g = 0; g < 2; ++g) {
      f32x4 hv0, hv1;
#pragma unroll
      for (int r = 0; r < 4; ++r) {
        hv0[r] = lrelu(acc[g][0][r] + gb0[r]);
        hv1[r] = lrelu(acc[g][1][r] + gb1[r]);
      }
      make_frags(hv0, hv1, b2h[g], b2l[g]);
    }
    // ---- GEMM2: shared w2 frags ----
#pragma unroll
    for (int mc = 0; mc < 4; ++mc) {
      short8 a2h[2], a2l[2];
#pragma unroll
      for (int u = 0; u < 2; ++u) {
        const int off = ((mc * 2 + u) * 4 + ko) * 512 + lane16;
        a2h[u] = *(const short8*)(w2h_l + off);
        a2l[u] = *(const short8*)(w2l_l + off);
      }
#pragma unroll
      for (int u = 0; u < 2; ++u) {
        const int ms = mc * 2 + u;
        acc2[0][ms] = mfma16(a2h[u], b2h[0], acc2[0][ms]);
        acc2[0][ms] = mfma16(a2l[u], b2h[0], acc2[0][ms]);
        acc2[0][ms] = mfma16(a2h[u], b2l[0], acc2[0][ms]);
        acc2[1][ms] = mfma16(a2h[u], b2h[1], acc2[1][ms]);
        acc2[1][ms] = mfma16(a2l[u], b2h[1], acc2[1][ms]);
        acc2[1][ms] = mfma16(a2h[u], b2l[1], acc2[1][ms]);
      }
    }
  }

  // ---- epilogue per group: residual + lrelu + mask; wsum RMW (zero-inited) ----
#pragma unroll
  for (int g = 0; g < 2; ++g) {
    const int grp = g0i + g;
    const float mk = maskp[grp * 16 + n16];
    float* base_w = xlf + (size_t)grp * 2048;
#pragma unroll
    for (int ms = 0; ms < 8; ++ms) {
      f32x4 lb4 = *(const f32x4*)&l2b_s[ms * 16 + q * 4];
      float* xo = base_w + ms * 256 + (q * 16 + n16) * 4;
      f32x4 old = *(const f32x4*)xo;
      f32x4 v;
#pragma unroll
      for (int r = 0; r < 4; ++r) v[r] = lrelu(acc2[g][ms][r] + lb4[r] + old[r]) * mk;
      *(f32x4*)xo = v;
      f32x4 sr;
#pragma unroll
      for (int r = 0; r < 4; ++r) {
        float s = v[r];
        s += __shfl_xor(s, 1, 64);
        s += __shfl_xor(s, 2, 64);
        s += __shfl_xor(s, 4, 64);
        s += __shfl_xor(s, 8, 64);
        sr[r] = s;
      }
      if (n16 == 0) {
        f32x4 tcur = *(const f32x4*)&wsum_row[ms * 16 + q * 4];
        tcur += sr;
        *(f32x4*)&wsum_row[ms * 16 + q * 4] = tcur;
      }
    }
  }
}

// ---- one group's K-loop + epilogue, LAST variant (verified r16) ----
template <bool LAST>
__device__ __forceinline__ void epic_pass(
    int g, int wv, int q, int n16, int lane16,
    const short8* xbh, const short8* xbl,
    const unsigned short* w1h_l, const unsigned short* w1l_l,
    const unsigned short* w2h_l, const unsigned short* w2l_l,
    const float* gbias_s, const float* l2b_s, const float* outw_s,
    float* wsum, float* __restrict__ xlf, const float* __restrict__ maskp,
    float* __restrict__ outp) {
  f32x4 acc2[8];
#pragma unroll
  for (int ms = 0; ms < 8; ++ms) acc2[ms] = (f32x4){0.f, 0.f, 0.f, 0.f};

#pragma unroll 1
  for (int ko = 0; ko < 4; ++ko) {
    f32x4 acc[2][2];
#pragma unroll
    for (int t = 0; t < 2; ++t)
#pragma unroll
      for (int kc = 0; kc < 2; ++kc) acc[t][kc] = (f32x4){0.f, 0.f, 0.f, 0.f};
#pragma unroll
    for (int t = 0; t < 2; ++t) {
#pragma unroll
      for (int kc = 0; kc < 2; ++kc) {
        short8 a1h[2], a1l[2];
#pragma unroll
        for (int u = 0; u < 2; ++u) {
          const int off = ((ko * 2 + t) * 4 + kc * 2 + u) * 512 + lane16;
          a1h[u] = *(const short8*)(w1h_l + off);
          a1l[u] = *(const short8*)(w1l_l + off);
        }
#pragma unroll
        for (int u = 0; u < 2; ++u) {
          const int ks = kc * 2 + u;
          acc[t][kc] = mfma16(a1h[u], xbh[ks], acc[t][kc]);
          acc[t][kc] = mfma16(a1l[u], xbh[ks], acc[t][kc]);
          acc[t][kc] = mfma16(a1h[u], xbl[ks], acc[t][kc]);
        }
      }
    }
    f32x4 gb0 = *(const f32x4*)&gbias_s[ko * 32 + q * 8];
    f32x4 gb1 = *(const f32x4*)&gbias_s[ko * 32 + q * 8 + 4];
    f32x4 hv0, hv1;
#pragma unroll
    for (int r = 0; r < 4; ++r) {
      hv0[r] = lrelu(acc[0][0][r] + acc[0][1][r] + gb0[r]);
      hv1[r] = lrelu(acc[1][0][r] + acc[1][1][r] + gb1[r]);
    }
    short8 b2h, b2l;
    make_frags(hv0, hv1, b2h, b2l);
#pragma unroll
    for (int mc = 0; mc < 4; ++mc) {
      short8 a2h[2], a2l[2];
#pragma unroll
      for (int u = 0; u < 2; ++u) {
        const int off = ((mc * 2 + u) * 4 + ko) * 512 + lane16;
        a2h[u] = *(const short8*)(w2h_l + off);
        a2l[u] = *(const short8*)(w2l_l + off);
      }
#pragma unroll
      for (int u = 0; u < 2; ++u) {
        const int ms = mc * 2 + u;
        acc2[ms] = mfma16(a2h[u], b2h, acc2[ms]);
        acc2[ms] = mfma16(a2l[u], b2h, acc2[ms]);
        acc2[ms] = mfma16(a2h[u], b2l, acc2[ms]);
      }
    }
  }

  const float mk = maskp[g * 16 + n16];
  float po[3];
  if (LAST) po[0] = po[1] = po[2] = 0.f;
  float* base_w = xlf + (size_t)g * 2048;
#pragma unroll
  for (int ms = 0; ms < 8; ++ms) {
    f32x4 lb4 = *(const f32x4*)&l2b_s[ms * 16 + q * 4];
    float* xo = base_w + ms * 256 + (q * 16 + n16) * 4;
    f32x4 old = *(const f32x4*)xo;
    f32x4 v;
#pragma unroll
    for (int r = 0; r < 4; ++r) v[r] = lrelu(acc2[ms][r] + lb4[r] + old[r]) * mk;
    if (!LAST) {
      *(f32x4*)xo = v;
      f32x4 sr;
#pragma unroll
      for (int r = 0; r < 4; ++r) {
        float s = v[r];
        s += __shfl_xor(s, 1, 64);
        s += __shfl_xor(s, 2, 64);
        s += __shfl_xor(s, 4, 64);
        s += __shfl_xor(s, 8, 64);
        sr[r] = s;
      }
      if (n16 == 0) *(f32x4*)&wsum[wv * 128 + ms * 16 + q * 4] = sr;
    } else {
      f32x4 w0 = *(const f32x4*)&outw_s[0 * 128 + ms * 16 + q * 4];
      f32x4 w1 = *(const f32x4*)&outw_s[1 * 128 + ms * 16 + q * 4];
      f32x4 w2 = *(const f32x4*)&outw_s[2 * 128 + ms * 16 + q * 4];
#pragma unroll
      for (int r = 0; r < 4; ++r) {
        po[0] += v[r] * w0[r];
        po[1] += v[r] * w1[r];
        po[2] += v[r] * w2[r];
      }
    }
  }
  if (LAST) {
#pragma unroll
    for (int o = 0; o < 3; ++o) {
      float s = po[o];
      s += __shfl_xor(s, 16, 64);
      s += __shfl_xor(s, 32, 64);
      po[o] = s;
    }
    if (q == 0) {
      const int p = g * 16 + n16;
#pragma unroll
      for (int o = 0; o < 3; ++o)
        outp[(size_t)p * 3 + o] = (po[o] + outw_s[384 + o]) * mk;
    }
  }
}

// ---------------- epic local: 256 WGs x 512 thr, 8 waves x 2 PAIRS ----------------
__global__ __launch_bounds__(512, 2) void epic_local_kernel(
    float* __restrict__ xlf, float* __restrict__ pP,
    const float* __restrict__ cnt_g, unsigned int* __restrict__ counters_blk,
    const float* __restrict__ gbias_in,
    const float* __restrict__ xg_tail_cur, float* __restrict__ xg_tail_next,
    float* __restrict__ gbias_tail_out,
    const float* __restrict__ context,
    const float* __restrict__ g1w_n, const float* __restrict__ g1b_n,
    const float* __restrict__ g2w_n, const float* __restrict__ g2b_n,
    const float* __restrict__ l1w_n, const float* __restrict__ l1b_n,
    const float* __restrict__ l2b,
    const unsigned short* __restrict__ w1h, const unsigned short* __restrict__ w1l,
    const unsigned short* __restrict__ w2h, const unsigned short* __restrict__ w2l,
    const float* __restrict__ maskp,
    float* __restrict__ outp) {
  __shared__ unsigned short wbuf[65536];  // 128 KB: w1h|w1l|w2h|w2l
  __shared__ float shx[768];
  __shared__ float gbias_s[128];
  __shared__ float l2b_s[128];
  __shared__ float wsum[1024];            // 8 waves x 128
  __shared__ int winflag;
  const int tid = threadIdx.x, bid = blockIdx.x;
  const int b = bid >> 4;   // 16 WGs per batch
  const int wv = tid >> 6, lane = tid & 63;
  const int q = lane >> 4, n16 = lane & 15;
  const int lane16 = lane * 8;

  // ---- Fix A: prefetch THIS dispatch's tail weights (16 spread WGs) ----
  float pfacc = 0.f;
  if ((bid & 15) == 0) {
    const int ch = bid >> 4;           // 0..15
    const int t0 = ch * 512 + tid, STR = 16 * 512;
    const float4* p;
    p = (const float4*)g1w_n; for (int i = t0; i < 9024; i += STR) pfacc += p[i].x;
    p = (const float4*)l1w_n; for (int i = t0; i < 4928; i += STR) pfacc += p[i].x;
    if (t0 < 320) pfacc += ((const float4*)g2w_n)[t0].x;
  }

  // ---- stage weights: wave wv stages 16 KB (16 x 1KB async) ----
  {
    const unsigned short* src =
        (wv < 2) ? w1h : (wv < 4) ? w1l : (wv < 6) ? w2h : w2l;
    const char* s8 = (const char*)(src + (wv & 1) * 8192) + lane * 16;
    char* d8 = (char*)wbuf + wv * 16384;
#pragma unroll
    for (int j = 0; j < 16; ++j) async_cp16(s8 + j * 1024, d8 + j * 1024);
  }
  if (tid < 128) {
    gbias_s[tid] = gbias_in[b * 128 + tid];
    l2b_s[tid] = l2b[tid];
  }
  // zero wave-private wsum row (no barrier needed: same-wave use only)
  if (lane < 32) *(f32x4*)&wsum[wv * 128 + lane * 4] = (f32x4){0.f, 0.f, 0.f, 0.f};

  // ---- pair-1 frags loaded before the drain barrier (overlap with DMA) ----
  const int g0 = bid * 32 + wv * 4;  // this wave's 4 groups
  short8 xh[2][4], xl2[2][4];
  load_frags(xlf + (size_t)g0 * 2048, q, n16, xh[0], xl2[0]);
  load_frags(xlf + (size_t)(g0 + 1) * 2048, q, n16, xh[1], xl2[1]);
  __syncthreads();  // staging drained (vmcnt 0) + all waves ready

  const unsigned short* w1h_l = wbuf;
  const unsigned short* w1l_l = wbuf + 16384;
  const unsigned short* w2h_l = wbuf + 32768;
  const unsigned short* w2l_l = wbuf + 49152;

  pair_pass2(g0, q, n16, lane16, xh, xl2, w1h_l, w1l_l, w2h_l, w2l_l,
             gbias_s, l2b_s, &wsum[wv * 128], xlf, maskp);
  asm volatile("" :: "v"(pfacc));  // prefetch DCE guard (loads long done)

  load_frags(xlf + (size_t)(g0 + 2) * 2048, q, n16, xh[0], xl2[0]);
  load_frags(xlf + (size_t)(g0 + 3) * 2048, q, n16, xh[1], xl2[1]);
  pair_pass2(g0 + 2, q, n16, lane16, xh, xl2, w1h_l, w1l_l, w2h_l, w2l_l,
             gbias_s, l2b_s, &wsum[wv * 128], xlf, maskp);

  __syncthreads();
  if (tid < 128) {
    float sA = wsum[0 * 128 + tid] + wsum[1 * 128 + tid] +
               wsum[2 * 128 + tid] + wsum[3 * 128 + tid];
    float sB = wsum[4 * 128 + tid] + wsum[5 * 128 + tid] +
               wsum[6 * 128 + tid] + wsum[7 * 128 + tid];
    agent_store(&pP[(size_t)(bid * 2) * 128 + tid], sA);
    agent_store(&pP[(size_t)(bid * 2 + 1) * 128 + tid], sB);
  }

  // ---- winner tail: next block's global path (threshold 16 WGs/batch) ----
  __syncthreads();
  if (tid == 0) winflag = (atomicAdd(&counters_blk[b], 1u) == 15u) ? 1 : 0;
  __syncthreads();
  if (!winflag) return;
  epic_global_tail<32>(b, tid, pP, cnt_g[b], xg_tail_cur + b * 16, xg_tail_next + b * 16,
                       context, g1w_n, g1b_n, g2w_n, g2b_n, l1w_n, l1b_n,
                       gbias_tail_out + (size_t)b * 128, shx);
}

// ---------------- LAST layer: 256 WGs x 512 thr (verified r16) ----------------
__global__ __launch_bounds__(512, 2) void epic_last_kernel(
    const float* __restrict__ xlf,
    const float* __restrict__ gbias_in,
    const float* __restrict__ l2b,
    const unsigned short* __restrict__ w1h, const unsigned short* __restrict__ w1l,
    const unsigned short* __restrict__ w2h, const unsigned short* __restrict__ w2l,
    const float* __restrict__ maskp,
    const float* __restrict__ outw, const float* __restrict__ outb,
    float* __restrict__ outp) {
  __shared__ unsigned short wbuf[65536];  // 128 KB
  __shared__ float gbias_s[128];
  __shared__ float l2b_s[128];
  __shared__ float outw_s[392];
  const int tid = threadIdx.x, bid = blockIdx.x;
  const int b = bid >> 4;
  const int wv = tid >> 6, lane = tid & 63;
  const int q = lane >> 4, n16 = lane & 15;
  const int lane16 = lane * 8;

  {
    const unsigned short* src =
        (wv < 2) ? w1h : (wv < 4) ? w1l : (wv < 6) ? w2h : w2l;
    const char* s8 = (const char*)(src + (wv & 1) * 8192) + lane * 16;
    char* d8 = (char*)wbuf + wv * 16384;
#pragma unroll
    for (int j = 0; j < 16; ++j) async_cp16(s8 + j * 1024, d8 + j * 1024);
  }
  if (tid < 128) {
    gbias_s[tid] = gbias_in[b * 128 + tid];
    l2b_s[tid] = l2b[tid];
  }
  if (tid < 384) outw_s[tid] = outw[tid];
  if (tid >= 384 && tid < 387) outw_s[tid] = outb[tid - 384];
  __syncthreads();

  const unsigned short* w1h_l = wbuf;
  const unsigned short* w1l_l = wbuf + 16384;
  const unsigned short* w2h_l = wbuf + 32768;
  const unsigned short* w2l_l = wbuf + 49152;

#pragma unroll 1
  for (int p4 = 0; p4 < 4; ++p4) {
    const int g = bid * 32 + wv * 4 + p4;
    short8 xbh[4], xbl[4];
    load_frags(xlf + (size_t)g * 2048, q, n16, xbh, xbl);
    epic_pass<true>(g, wv, q, n16, lane16, xbh, xbl, w1h_l, w1l_l, w2h_l, w2l_l,
                    gbias_s, l2b_s, outw_s, gbias_s /*dead*/,
                    const_cast<float*>(xlf), maskp, outp);
  }
}

extern "C" void kernel_launch(void* const* d_in, const int* in_sizes, int n_in,
                              void* d_out, int out_size, void* d_ws, size_t ws_size,
                              hipStream_t stream) {
  const float* x_local = (const float*)d_in[0];
  const float* context = (const float*)d_in[1];
  const float* mask = (const float*)d_in[2];
  const float* proj_lw = (const float*)d_in[3];
  const float* proj_lb = (const float*)d_in[4];
  const float* proj_g0w = (const float*)d_in[5];
  const float* proj_g0b = (const float*)d_in[6];
  const float* proj_g1w = (const float*)d_in[7];
  const float* proj_g1b = (const float*)d_in[8];
  const float* proj_g2w = (const float*)d_in[9];
  const float* proj_g2b = (const float*)d_in[10];
  const float* g1w = (const float*)d_in[11];
  const float* g1b = (const float*)d_in[12];
  const float* g2w = (const float*)d_in[13];
  const float* g2b = (const float*)d_in[14];
  const float* l1w = (const float*)d_in[15];
  const float* l1b = (const float*)d_in[16];
  const float* l2w = (const float*)d_in[17];
  const float* l2b = (const float*)d_in[18];
  const float* outw = (const float*)d_in[19];
  const float* outb = (const float*)d_in[20];
  float* out = (float*)d_out;

  char* ws = (char*)d_ws;
  float* xlf = (float*)ws;                                  // 67,108,864
  float* pP = (float*)(ws + 67108864);                      //  1,048,576
  float* cntp = (float*)(ws + 68157440);                    //      4,096
  float* cnt_g = (float*)(ws + 68161536);                   //         64
  float* xg_g = (float*)(ws + 68161600);                    //      7,168
  float* gbias_g = (float*)(ws + 68168768);                 //     49,152
  unsigned int* counters = (unsigned int*)(ws + 68217920);  //        448
  unsigned short* w1h = (unsigned short*)(ws + 68218368);   //    196,608
  unsigned short* w1l = (unsigned short*)(ws + 68414976);   //    196,608
  unsigned short* w2h = (unsigned short*)(ws + 68611584);   //    196,608
  unsigned short* w2l = (unsigned short*)(ws + 68808192);   //    196,608
  // end: 69,004,800 (< proven 70,018,304)

  prep_weights<<<384, 256, 0, stream>>>(l1w, l2w, w1h, w1l, w2h, w2l, counters);
  proj_local_kernel<<<1024, 256, 0, stream>>>(
      x_local, mask, proj_lw, proj_lb, xlf, pP, cntp, cnt_g, counters, context,
      proj_g0w, proj_g0b, proj_g1w, proj_g1b, proj_g2w, proj_g2b, xg_g,
      g1w, g1b, g2w, g2b, l1w, l1b, gbias_g);
  for (int i = 0; i < NB_; ++i) {
    const int j = i + 1;  // next block (tail target)
    const float* g1w_n = g1w + (size_t)j * 128 * 282;
    const float* g1b_n = g1b + j * 128;
    const float* g2w_n = g2w + j * 10 * 128;
    const float* g2b_n = g2b + j * 10;
    const float* l1w_n = l1w + (size_t)j * 128 * 154;
    const float* l1b_n = l1b + j * 128;
    const unsigned short* w1h_i = w1h + i * 16384;
    const unsigned short* w1l_i = w1l + i * 16384;
    const unsigned short* w2h_i = w2h + i * 16384;
    const unsigned short* w2l_i = w2l + i * 16384;
    if (i == NB_ - 1) {
      epic_last_kernel<<<256, 512, 0, stream>>>(
          xlf, gbias_g + (size_t)(i * 16) * 128, l2b + i * 128,
          w1h_i, w1l_i, w2h_i, w2l_i, mask, outw, outb, out);
    } else {
      epic_local_kernel<<<256, 512, 0, stream>>>(
          xlf, pP, cnt_g, counters + (i + 1) * 16, gbias_g + (size_t)(i * 16) * 128,
          xg_g + (i + 1) * 16 * 16, xg_g + (i + 2) * 16 * 16,
          gbias_g + (size_t)((i + 1) * 16) * 128, context,
          g1w_n, g1b_n, g2w_n, g2b_n, l1w_n, l1b_n,
          l2b + i * 128, w1h_i, w1l_i, w2h_i, w2l_i, mask, out);
    }
  }
}

// Round 7
// 450.531 us; speedup vs baseline: 1.0384x; 1.0384x over previous
//
#include <hip/hip_runtime.h>
#include <hip/hip_bf16.h>

// EPiC network, round 18: r16 base restored (447us, verified) + prefetch only.
// r17 post-mortem: pairing (Fix B) spilled — VGPR capped 128, FETCH +29MB
// (scratch), epic_local 61.6->90us. REVERTED to r16's 1024-thr epic_local
// (60 VGPR, no spill). Fix A (tail-weight prefetch into L2/L3 by spread WGs,
// DCE-guarded) KEPT — this round is a clean A/B: r16 measured proj=62.2,
// epic_local=61.6 with zero other diffs.
// Next candidate if prefetch pays: 32-pt groups via mfma 32x32x16 (halves
// weight LDS reads per point without doubling live regs).

typedef __attribute__((ext_vector_type(8))) short short8;
typedef __attribute__((ext_vector_type(4))) float f32x4;

#define B_ 16
#define N_ 8192
#define DC_ 16
#define H_ 128
#define G_ 10
#define NB_ 6
#define NEG_ 0.01f

__device__ __forceinline__ float lrelu(float x) { return x > 0.f ? x : NEG_ * x; }

__device__ __forceinline__ unsigned short f2bf(float x) {
  union { float f; unsigned u; } v; v.f = x;
  return (unsigned short)((v.u + 0x7fffu + ((v.u >> 16) & 1u)) >> 16);  // RNE
}
__device__ __forceinline__ float bf2f(unsigned short u) {
  union { unsigned u; float f; } v; v.u = ((unsigned)u) << 16; return v.f;
}
// truncating hi (1 op) + RNE lo of residual; pair represents x to ~2^-17
__device__ __forceinline__ void split_bf(float x, unsigned short& h, unsigned short& l) {
  union { float f; unsigned u; } v; v.f = x;
  unsigned hu = v.u & 0xffff0000u;
  h = (unsigned short)(hu >> 16);
  union { unsigned u; float f; } hv; hv.u = hu;
  l = f2bf(x - hv.f);
}

__device__ __forceinline__ f32x4 mfma16(short8 a, short8 b, f32x4 c) {
  return __builtin_amdgcn_mfma_f32_16x16x32_bf16(a, b, c, 0, 0, 0);
}

__device__ __forceinline__ void make_frags(f32x4 v0, f32x4 v1, short8& bh, short8& bl) {
  unsigned short h, l;
#pragma unroll
  for (int j = 0; j < 4; ++j) {
    split_bf(v0[j], h, l);
    bh[j] = (short)h; bl[j] = (short)l;
  }
#pragma unroll
  for (int j = 0; j < 4; ++j) {
    split_bf(v1[j], h, l);
    bh[4 + j] = (short)h; bl[4 + j] = (short)l;
  }
}

// async 16B-per-lane global -> LDS copy (lane-contiguous DMA)
__device__ __forceinline__ void async_cp16(const void* g, void* l) {
  __builtin_amdgcn_global_load_lds(
      (const __attribute__((address_space(1))) void*)g,
      (__attribute__((address_space(3))) void*)l, 16, 0, 0);
}

// agent-scope write-through publication (no L2 flush)
__device__ __forceinline__ void agent_store(float* p, float v) {
  __hip_atomic_store(p, v, __ATOMIC_RELAXED, __HIP_MEMORY_SCOPE_AGENT);
}
__device__ __forceinline__ float agent_load(const float* p) {
  return __hip_atomic_load(p, __ATOMIC_RELAXED, __HIP_MEMORY_SCOPE_AGENT);
}

// ---- common tail: pool(NS slots) -> h_g -> xg residual -> folded gbias ----
// Works for blockDim 256/512/1024: compute guarded, barriers unconditional.
template <int NS>
__device__ void epic_global_tail(
    int b, int tid, const float* __restrict__ pP, float cnt,
    const float* __restrict__ xg_cur, float* __restrict__ xg_next,
    const float* __restrict__ context,
    const float* __restrict__ g1w_n, const float* __restrict__ g1b_n,
    const float* __restrict__ g2w_n, const float* __restrict__ g2b_n,
    const float* __restrict__ l1w_n, const float* __restrict__ l1b_n,
    float* __restrict__ gbias_out, float* shx) {
  if (tid < 256) {
    const int f = tid & 127, kh = tid >> 7;
    const float* pr = pP + ((size_t)b * NS + kh * (NS / 2)) * 128 + f;
    float s = 0.f;
#pragma unroll 8
    for (int w = 0; w < NS / 2; ++w) s += agent_load(pr + w * 128);
    shx[tid] = s;
  }
  __syncthreads();
  if (tid < 128) {
    float s = shx[tid] + shx[tid + 128];
    shx[384 + tid] = s;
    shx[256 + tid] = s / cnt;
  }
  if (tid < G_) shx[512 + tid] = xg_cur[tid];
  if (tid >= 32 && tid < 32 + DC_) shx[522 + tid - 32] = context[b * DC_ + tid - 32];
  __syncthreads();
  if (tid < 256) {
    const int f = tid & 127, kh = tid >> 7;
    const float* wr = g1w_n + (size_t)f * 282 + kh * 142;
    const float* vp = shx + 256 + kh * 142;
    const int n2 = kh ? 70 : 71;
    float a = 0.f;
#pragma unroll 8
    for (int j = 0; j < n2; ++j) {
      float2 w2 = *(const float2*)(wr + 2 * j);
      a += w2.x * vp[2 * j] + w2.y * vp[2 * j + 1];
    }
    shx[tid] = a;  // writes 0..255; reads were 256..539 (disjoint)
  }
  __syncthreads();
  if (tid < 128) shx[544 + tid] = lrelu(shx[tid] + shx[tid + 128] + g1b_n[tid]);
  __syncthreads();
  if (tid < G_) {
    const float* wr = g2w_n + tid * 128;
    float a = g2b_n[tid] + shx[512 + tid];
#pragma unroll 8
    for (int j = 0; j < 32; ++j) {
      float4 w4 = *(const float4*)(wr + 4 * j);
      a += w4.x * shx[544 + 4 * j] + w4.y * shx[544 + 4 * j + 1] +
           w4.z * shx[544 + 4 * j + 2] + w4.w * shx[544 + 4 * j + 3];
    }
    float v = lrelu(a);
    shx[672 + tid] = v;
    xg_next[tid] = v;
  }
  __syncthreads();
  if (tid < 128) {
    const float* wr = l1w_n + tid * 154;
    float a = l1b_n[tid];
#pragma unroll
    for (int j = 0; j < G_; ++j) a += wr[128 + j] * shx[672 + j];
#pragma unroll
    for (int j = 0; j < DC_; ++j) a += wr[138 + j] * shx[522 + j];
    gbias_out[tid] = a;
  }
}

// ---------------- weight prep: split + frag-order swizzle ----------------
__global__ __launch_bounds__(256) void prep_weights(
    const float* __restrict__ l1w, const float* __restrict__ l2w,
    unsigned short* __restrict__ w1h, unsigned short* __restrict__ w1l,
    unsigned short* __restrict__ w2h, unsigned short* __restrict__ w2l,
    unsigned int* __restrict__ counters) {
  int idx = blockIdx.x * 256 + threadIdx.x;
  const int total = NB_ * H_ * H_;
  if (idx < 112) counters[idx] = 0u;
  if (idx < total) {
    int i = idx / (H_ * H_), rem = idx % (H_ * H_);
    int F = rem / H_, k = rem % H_;
    int ks = k >> 5, c = k & 31;
    int mt2 = F >> 4, r2 = F & 15;
    int mt1 = ((F >> 5) << 1) | ((F >> 2) & 1);
    int r1 = (((F >> 3) & 3) << 2) | (F & 3);
    int off1 = i * 16384 + (mt1 * 4 + ks) * 512 + ((c >> 3) * 16 + r1) * 8 + (c & 7);
    int off2 = i * 16384 + (mt2 * 4 + ks) * 512 + ((c >> 3) * 16 + r2) * 8 + (c & 7);
    unsigned short h, l;
    split_bf(l1w[(i * H_ + F) * 154 + k], h, l);
    w1h[off1] = h; w1l[off1] = l;
    split_bf(l2w[(i * H_ + F) * H_ + k], h, l);
    w2h[off2] = h; w2l[off2] = l;
  }
}

// ---------------- projection local (writes 16-pt-group xl) + proj/blk0 tail ----
__global__ __launch_bounds__(256, 2) void proj_local_kernel(
    const float* __restrict__ xloc, const float* __restrict__ maskp,
    const float* __restrict__ plw, const float* __restrict__ plb,
    float* __restrict__ xlf, float* __restrict__ pP,
    float* __restrict__ cntp, float* __restrict__ cnt_g,
    unsigned int* __restrict__ counters,
    const float* __restrict__ context,
    const float* __restrict__ g0w, const float* __restrict__ g0b,
    const float* __restrict__ g1pw, const float* __restrict__ g1pb,
    const float* __restrict__ g2pw, const float* __restrict__ g2pb,
    float* __restrict__ xg_g,
    const float* __restrict__ g1w0, const float* __restrict__ g1b0,
    const float* __restrict__ g2w0, const float* __restrict__ g2b0,
    const float* __restrict__ l1w0, const float* __restrict__ l1b0,
    float* __restrict__ gbias_g) {
  __shared__ float wq[H_][4];
  __shared__ float wsum[512];
  __shared__ float cw[4];
  __shared__ float shx[768];
  __shared__ int winflag;
  const int tid = threadIdx.x, bid = blockIdx.x;
  const int wv = tid >> 6, lane = tid & 63;
  const int q = lane >> 4, n16 = lane & 15;
  const int b = bid >> 6;

  // ---- Fix A: prefetch tail weights into L2/L3 (32 spread WGs) ----
  float pfacc = 0.f;
  if ((bid & 31) == 0) {
    const int ch = bid >> 5;           // 0..31
    const int t0 = ch * 256 + tid, STR = 32 * 256;
    const float4* p;
    p = (const float4*)g0w;  for (int i = t0; i < 8704; i += STR) pfacc += p[i].x;
    p = (const float4*)g1pw; for (int i = t0; i < 4096; i += STR) pfacc += p[i].x;
    p = (const float4*)g1w0; for (int i = t0; i < 9024; i += STR) pfacc += p[i].x;
    p = (const float4*)l1w0; for (int i = t0; i < 4928; i += STR) pfacc += p[i].x;
    if (t0 < 320) pfacc += ((const float4*)g2pw)[t0].x + ((const float4*)g2w0)[t0].x;
  }

  if (tid < H_) {
    wq[tid][0] = plw[tid * 3 + 0];
    wq[tid][1] = plw[tid * 3 + 1];
    wq[tid][2] = plw[tid * 3 + 2];
    wq[tid][3] = plb[tid];
  }
  __syncthreads();
  const int t = bid * 4 + wv;            // 32-pt tile index
  const int p0 = t * 32;
  const int pa = p0 + n16, pb = p0 + 16 + n16;
  const float xa0 = xloc[pa * 3], xa1 = xloc[pa * 3 + 1], xa2 = xloc[pa * 3 + 2];
  const float xb0 = xloc[pb * 3], xb1 = xloc[pb * 3 + 1], xb2 = xloc[pb * 3 + 2];
  const float m0 = maskp[pa], m1 = maskp[pb];
  float* ga = xlf + (size_t)(2 * t) * 2048;
  float* gb = ga + 2048;
#pragma unroll
  for (int ms = 0; ms < 8; ++ms) {
    f32x4 v0, v1;
#pragma unroll
    for (int r = 0; r < 4; ++r) {
      const int F = ms * 16 + q * 4 + r;
      float4 w4 = *(const float4*)wq[F];
      v0[r] = lrelu(w4.x * xa0 + w4.y * xa1 + w4.z * xa2 + w4.w) * m0;
      v1[r] = lrelu(w4.x * xb0 + w4.y * xb1 + w4.z * xb2 + w4.w) * m1;
    }
    *(f32x4*)(ga + ms * 256 + (q * 16 + n16) * 4) = v0;
    *(f32x4*)(gb + ms * 256 + (q * 16 + n16) * 4) = v1;
    f32x4 s = v0 + v1;
#pragma unroll
    for (int r = 0; r < 4; ++r) {
      float sv = s[r];
      sv += __shfl_xor(sv, 1, 64);
      sv += __shfl_xor(sv, 2, 64);
      sv += __shfl_xor(sv, 4, 64);
      sv += __shfl_xor(sv, 8, 64);
      s[r] = sv;
    }
    if (n16 == 0) *(f32x4*)&wsum[wv * 128 + ms * 16 + q * 4] = s;
  }
  {
    float c = (q == 0) ? (m0 + m1) : 0.f;
    c += __shfl_xor(c, 1, 64);
    c += __shfl_xor(c, 2, 64);
    c += __shfl_xor(c, 4, 64);
    c += __shfl_xor(c, 8, 64);
    if (lane == 0) cw[wv] = c;
  }
  __syncthreads();
  // two 64-pt slots per WG -> 128 slots per batch
  if (tid < 128) {
    agent_store(&pP[(size_t)(2 * bid) * 128 + tid], wsum[tid] + wsum[128 + tid]);
    agent_store(&pP[(size_t)(2 * bid + 1) * 128 + tid], wsum[256 + tid] + wsum[384 + tid]);
  }
  if (tid == 0) agent_store(&cntp[bid], cw[0] + cw[1] + cw[2] + cw[3]);
  asm volatile("" :: "v"(pfacc));  // keep prefetch loads live (rule #17)

  // ---- winner tail: proj global path + block-0 global path ----
  __syncthreads();
  if (tid == 0) winflag = (atomicAdd(&counters[b], 1u) == 63u) ? 1 : 0;
  __syncthreads();
  if (!winflag) return;
  if (tid < 64) shx[688 + tid] = agent_load(&cntp[b * 64 + tid]);
  __syncthreads();
  if (tid == 0) {
    float c = 0.f;
#pragma unroll
    for (int w = 0; w < 64; ++w) c += shx[688 + w];
    shx[752] = c;
    cnt_g[b] = c;
  }
  __syncthreads();
  const float cnt = shx[752];
  {
    const int f = tid & 127, kh = tid >> 7;
    const float* pr = pP + ((size_t)b * 128 + kh * 64) * 128 + f;
    float s = 0.f;
#pragma unroll 8
    for (int w = 0; w < 64; ++w) s += agent_load(pr + w * 128);
    shx[tid] = s;
  }
  __syncthreads();
  if (tid < 128) {
    float s = shx[tid] + shx[tid + 128];
    shx[384 + tid] = s;
    shx[256 + tid] = s / cnt;
  }
  if (tid < DC_) shx[512 + tid] = context[b * DC_ + tid];
  __syncthreads();
  {
    const int f = tid & 127, kh = tid >> 7;
    const float* wr = g0w + (size_t)f * 272 + kh * 136;
    const float* vp = shx + 256 + kh * 136;
    float a = 0.f;
#pragma unroll 8
    for (int j = 0; j < 34; ++j) {
      float4 w4 = *(const float4*)(wr + 4 * j);
      a += w4.x * vp[4 * j] + w4.y * vp[4 * j + 1] + w4.z * vp[4 * j + 2] + w4.w * vp[4 * j + 3];
    }
    __syncthreads();
    shx[tid] = a;
  }
  __syncthreads();
  if (tid < 128) shx[544 + tid] = lrelu(shx[tid] + shx[tid + 128] + g0b[tid]);
  __syncthreads();
  {
    const int f = tid & 127, kh = tid >> 7;
    const float* wr = g1pw + (size_t)f * 128 + kh * 64;
    const float* vp = shx + 544 + kh * 64;
    float a = 0.f;
#pragma unroll 8
    for (int j = 0; j < 16; ++j) {
      float4 w4 = *(const float4*)(wr + 4 * j);
      a += w4.x * vp[4 * j] + w4.y * vp[4 * j + 1] + w4.z * vp[4 * j + 2] + w4.w * vp[4 * j + 3];
    }
    __syncthreads();
    shx[tid] = a;
  }
  __syncthreads();
  if (tid < 128) shx[544 + tid] = lrelu(shx[tid] + shx[tid + 128] + g1pb[tid]);
  __syncthreads();
  if (tid < G_) {
    const float* wr = g2pw + tid * 128;
    float a = g2pb[tid];
#pragma unroll 8
    for (int j = 0; j < 32; ++j) {
      float4 w4 = *(const float4*)(wr + 4 * j);
      a += w4.x * shx[544 + 4 * j] + w4.y * shx[544 + 4 * j + 1] +
           w4.z * shx[544 + 4 * j + 2] + w4.w * shx[544 + 4 * j + 3];
    }
    xg_g[(0 * 16 + b) * 16 + tid] = lrelu(a);
  }
  __syncthreads();
  epic_global_tail<128>(b, tid, pP, cnt,
                        xg_g + (0 * 16 + b) * 16, xg_g + (1 * 16 + b) * 16, context,
                        g1w0, g1b0, g2w0, g2b0, l1w0, l1b0,
                        gbias_g + (size_t)(0 * 16 + b) * 128, shx);
}

// ---- per-group x B-frag load (B-layout, verified) ----
__device__ __forceinline__ void load_frags(const float* base_g, int q, int n16,
                                           short8* xbh, short8* xbl) {
#pragma unroll
  for (int ks = 0; ks < 4; ++ks) {
    const float* pb = base_g + (2 * ks + (q >> 1)) * 256 + ((q & 1) * 32 + n16) * 4;
    f32x4 v0 = *(const f32x4*)pb;
    f32x4 v1 = *(const f32x4*)(pb + 64);
    make_frags(v0, v1, xbh[ks], xbl[ks]);
  }
}

// ---- one group's K-loop + epilogue (GEMM1 split-acc, GEMM2, residual) ----
template <bool LAST>
__device__ __forceinline__ void epic_pass(
    int g, int wv, int q, int n16, int lane16,
    const short8* xbh, const short8* xbl,
    const unsigned short* w1h_l, const unsigned short* w1l_l,
    const unsigned short* w2h_l, const unsigned short* w2l_l,
    const float* gbias_s, const float* l2b_s, const float* outw_s,
    float* wsum, float* __restrict__ xlf, const float* __restrict__ maskp,
    float* __restrict__ outp) {
  f32x4 acc2[8];
#pragma unroll
  for (int ms = 0; ms < 8; ++ms) acc2[ms] = (f32x4){0.f, 0.f, 0.f, 0.f};

#pragma unroll 1
  for (int ko = 0; ko < 4; ++ko) {
    // ---- GEMM1: row-permuted w1 frags; split accumulators (chain depth 6) ----
    f32x4 acc[2][2];
#pragma unroll
    for (int t = 0; t < 2; ++t)
#pragma unroll
      for (int kc = 0; kc < 2; ++kc) acc[t][kc] = (f32x4){0.f, 0.f, 0.f, 0.f};
#pragma unroll
    for (int t = 0; t < 2; ++t) {
#pragma unroll
      for (int kc = 0; kc < 2; ++kc) {  // ks chunks of 2 (16 transient regs)
        short8 a1h[2], a1l[2];
#pragma unroll
        for (int u = 0; u < 2; ++u) {
          const int off = ((ko * 2 + t) * 4 + kc * 2 + u) * 512 + lane16;
          a1h[u] = *(const short8*)(w1h_l + off);
          a1l[u] = *(const short8*)(w1l_l + off);
        }
#pragma unroll
        for (int u = 0; u < 2; ++u) {
          const int ks = kc * 2 + u;
          acc[t][kc] = mfma16(a1h[u], xbh[ks], acc[t][kc]);
          acc[t][kc] = mfma16(a1l[u], xbh[ks], acc[t][kc]);
          acc[t][kc] = mfma16(a1h[u], xbl[ks], acc[t][kc]);
        }
      }
    }
    // ---- lane-local h -> GEMM2 B-frags (identity in k thanks to w1 perm) ----
    f32x4 gb0 = *(const f32x4*)&gbias_s[ko * 32 + q * 8];
    f32x4 gb1 = *(const f32x4*)&gbias_s[ko * 32 + q * 8 + 4];
    f32x4 hv0, hv1;
#pragma unroll
    for (int r = 0; r < 4; ++r) {
      hv0[r] = lrelu(acc[0][0][r] + acc[0][1][r] + gb0[r]);
      hv1[r] = lrelu(acc[1][0][r] + acc[1][1][r] + gb1[r]);
    }
    short8 b2h, b2l;
    make_frags(hv0, hv1, b2h, b2l);
    // ---- GEMM2: w2 frags from LDS, mi chunks of 2 ----
#pragma unroll
    for (int mc = 0; mc < 4; ++mc) {
      short8 a2h[2], a2l[2];
#pragma unroll
      for (int u = 0; u < 2; ++u) {
        const int off = ((mc * 2 + u) * 4 + ko) * 512 + lane16;
        a2h[u] = *(const short8*)(w2h_l + off);
        a2l[u] = *(const short8*)(w2l_l + off);
      }
#pragma unroll
      for (int u = 0; u < 2; ++u) {
        const int ms = mc * 2 + u;
        acc2[ms] = mfma16(a2h[u], b2h, acc2[ms]);
        acc2[ms] = mfma16(a2l[u], b2h, acc2[ms]);
        acc2[ms] = mfma16(a2h[u], b2l, acc2[ms]);
      }
    }
  }

  // ---- epilogue: residual + lrelu + mask ----
  const float mk = maskp[g * 16 + n16];
  float po[3];
  if (LAST) po[0] = po[1] = po[2] = 0.f;
  float* base_w = xlf + (size_t)g * 2048;
#pragma unroll
  for (int ms = 0; ms < 8; ++ms) {
    f32x4 lb4 = *(const f32x4*)&l2b_s[ms * 16 + q * 4];
    float* xo = base_w + ms * 256 + (q * 16 + n16) * 4;
    f32x4 old = *(const f32x4*)xo;
    f32x4 v;
#pragma unroll
    for (int r = 0; r < 4; ++r) v[r] = lrelu(acc2[ms][r] + lb4[r] + old[r]) * mk;
    if (!LAST) {
      *(f32x4*)xo = v;
      // reduce over point lanes; single group -> reduce v directly
      f32x4 sr;
#pragma unroll
      for (int r = 0; r < 4; ++r) {
        float s = v[r];
        s += __shfl_xor(s, 1, 64);
        s += __shfl_xor(s, 2, 64);
        s += __shfl_xor(s, 4, 64);
        s += __shfl_xor(s, 8, 64);
        sr[r] = s;
      }
      if (n16 == 0) *(f32x4*)&wsum[wv * 128 + ms * 16 + q * 4] = sr;
    } else {
      f32x4 w0 = *(const f32x4*)&outw_s[0 * 128 + ms * 16 + q * 4];
      f32x4 w1 = *(const f32x4*)&outw_s[1 * 128 + ms * 16 + q * 4];
      f32x4 w2 = *(const f32x4*)&outw_s[2 * 128 + ms * 16 + q * 4];
#pragma unroll
      for (int r = 0; r < 4; ++r) {
        po[0] += v[r] * w0[r];
        po[1] += v[r] * w1[r];
        po[2] += v[r] * w2[r];
      }
    }
  }
  if (LAST) {
#pragma unroll
    for (int o = 0; o < 3; ++o) {
      float s = po[o];
      s += __shfl_xor(s, 16, 64);
      s += __shfl_xor(s, 32, 64);
      po[o] = s;
    }
    if (q == 0) {
      const int p = g * 16 + n16;
#pragma unroll
      for (int o = 0; o < 3; ++o)
        outp[(size_t)p * 3 + o] = (po[o] + outw_s[384 + o]) * mk;
    }
  }
}

// ---------------- epic local: 256 WGs, 16 waves, 2 sequential 16-pt groups ----
__global__ __launch_bounds__(1024) void epic_local_kernel(
    float* __restrict__ xlf, float* __restrict__ pP,
    const float* __restrict__ cnt_g, unsigned int* __restrict__ counters_blk,
    const float* __restrict__ gbias_in,
    const float* __restrict__ xg_tail_cur, float* __restrict__ xg_tail_next,
    float* __restrict__ gbias_tail_out,
    const float* __restrict__ context,
    const float* __restrict__ g1w_n, const float* __restrict__ g1b_n,
    const float* __restrict__ g2w_n, const float* __restrict__ g2b_n,
    const float* __restrict__ l1w_n, const float* __restrict__ l1b_n,
    const float* __restrict__ l2b,
    const unsigned short* __restrict__ w1h, const unsigned short* __restrict__ w1l,
    const unsigned short* __restrict__ w2h, const unsigned short* __restrict__ w2l,
    const float* __restrict__ maskp,
    float* __restrict__ outp) {
  __shared__ unsigned short wbuf[65536];  // 128 KB: w1h|w1l|w2h|w2l, 16384 shorts each
  __shared__ float shx[768];
  __shared__ float gbias_s[128];
  __shared__ float l2b_s[128];
  __shared__ float wsum[2048];
  __shared__ int winflag;
  const int tid = threadIdx.x, bid = blockIdx.x;
  const int b = bid >> 4;   // 16 WGs per batch
  const int wv = tid >> 6, lane = tid & 63;
  const int q = lane >> 4, n16 = lane & 15;

  // ---- Fix A: prefetch THIS dispatch's tail weights (16 spread WGs) ----
  float pfacc = 0.f;
  if ((bid & 15) == 0) {
    const int ch = bid >> 4;           // 0..15
    const int t0 = ch * 1024 + tid, STR = 16 * 1024;
    const float4* p;
    p = (const float4*)g1w_n; for (int i = t0; i < 9024; i += STR) pfacc += p[i].x;
    p = (const float4*)l1w_n; for (int i = t0; i < 4928; i += STR) pfacc += p[i].x;
    if (t0 < 320) pfacc += ((const float4*)g2w_n)[t0].x;
  }

  // ---- stage weights ONCE: wave wv stages 8 KB (8 x 1KB async) ----
  {
    const unsigned short* src =
        (wv < 4) ? w1h : (wv < 8) ? w1l : (wv < 12) ? w2h : w2l;
    const char* s8 = (const char*)(src + (wv & 3) * 4096) + lane * 16;
    char* d8 = (char*)wbuf + wv * 8192;  // wave-uniform dest (lane*16 implicit)
#pragma unroll
    for (int j = 0; j < 8; ++j) async_cp16(s8 + j * 1024, d8 + j * 1024);
  }
  if (tid < 128) {
    gbias_s[tid] = gbias_in[b * 128 + tid];
    l2b_s[tid] = l2b[tid];
  }

  // ---- group A frags loaded before the drain barrier (overlap with DMA) ----
  const int gA = bid * 32 + wv;       // groups [bid*32, bid*32+16)
  const int gB = bid * 32 + 16 + wv;  // groups [bid*32+16, bid*32+32)
  short8 xbh[4], xbl[4];
  load_frags(xlf + (size_t)gA * 2048, q, n16, xbh, xbl);
  __syncthreads();  // staging drained (vmcnt 0) + all waves ready

  const unsigned short* w1h_l = wbuf;
  const unsigned short* w1l_l = wbuf + 16384;
  const unsigned short* w2h_l = wbuf + 32768;
  const unsigned short* w2l_l = wbuf + 49152;
  const int lane16 = lane * 8;  // shorts

  // ---- pass A ----
  epic_pass<false>(gA, wv, q, n16, lane16, xbh, xbl, w1h_l, w1l_l, w2h_l, w2l_l,
                   gbias_s, l2b_s, nullptr, wsum, xlf, maskp, outp);
  __syncthreads();
  if (tid < 128) {
    float s = 0.f;
#pragma unroll
    for (int w = 0; w < 16; ++w) s += wsum[w * 128 + tid];
    agent_store(&pP[(size_t)(bid * 2) * 128 + tid], s);
  }
  __syncthreads();  // protect wsum before pass B overwrites

  // ---- pass B (weights already resident; xlf slices disjoint from pass A) ----
  load_frags(xlf + (size_t)gB * 2048, q, n16, xbh, xbl);
  epic_pass<false>(gB, wv, q, n16, lane16, xbh, xbl, w1h_l, w1l_l, w2h_l, w2l_l,
                   gbias_s, l2b_s, nullptr, wsum, xlf, maskp, outp);
  __syncthreads();
  if (tid < 128) {
    float s = 0.f;
#pragma unroll
    for (int w = 0; w < 16; ++w) s += wsum[w * 128 + tid];
    agent_store(&pP[(size_t)(bid * 2 + 1) * 128 + tid], s);
  }
  asm volatile("" :: "v"(pfacc));  // prefetch DCE guard (rule #17)

  // ---- winner tail: next block's global path (threshold 16 WGs/batch) ----
  __syncthreads();
  if (tid == 0) winflag = (atomicAdd(&counters_blk[b], 1u) == 15u) ? 1 : 0;
  __syncthreads();
  if (!winflag) return;
  epic_global_tail<32>(b, tid, pP, cnt_g[b], xg_tail_cur + b * 16, xg_tail_next + b * 16,
                       context, g1w_n, g1b_n, g2w_n, g2b_n, l1w_n, l1b_n,
                       gbias_tail_out + (size_t)b * 128, shx);
}

// ---------------- LAST layer: 256 WGs x 512 thr (verified r16) ----------------
__global__ __launch_bounds__(512, 2) void epic_last_kernel(
    const float* __restrict__ xlf,
    const float* __restrict__ gbias_in,
    const float* __restrict__ l2b,
    const unsigned short* __restrict__ w1h, const unsigned short* __restrict__ w1l,
    const unsigned short* __restrict__ w2h, const unsigned short* __restrict__ w2l,
    const float* __restrict__ maskp,
    const float* __restrict__ outw, const float* __restrict__ outb,
    float* __restrict__ outp) {
  __shared__ unsigned short wbuf[65536];  // 128 KB
  __shared__ float gbias_s[128];
  __shared__ float l2b_s[128];
  __shared__ float outw_s[392];
  const int tid = threadIdx.x, bid = blockIdx.x;
  const int b = bid >> 4;
  const int wv = tid >> 6, lane = tid & 63;
  const int q = lane >> 4, n16 = lane & 15;
  const int lane16 = lane * 8;

  {
    const unsigned short* src =
        (wv < 2) ? w1h : (wv < 4) ? w1l : (wv < 6) ? w2h : w2l;
    const char* s8 = (const char*)(src + (wv & 1) * 8192) + lane * 16;
    char* d8 = (char*)wbuf + wv * 16384;
#pragma unroll
    for (int j = 0; j < 16; ++j) async_cp16(s8 + j * 1024, d8 + j * 1024);
  }
  if (tid < 128) {
    gbias_s[tid] = gbias_in[b * 128 + tid];
    l2b_s[tid] = l2b[tid];
  }
  if (tid < 384) outw_s[tid] = outw[tid];
  if (tid >= 384 && tid < 387) outw_s[tid] = outb[tid - 384];
  __syncthreads();

  const unsigned short* w1h_l = wbuf;
  const unsigned short* w1l_l = wbuf + 16384;
  const unsigned short* w2h_l = wbuf + 32768;
  const unsigned short* w2l_l = wbuf + 49152;

#pragma unroll 1
  for (int p4 = 0; p4 < 4; ++p4) {
    const int g = bid * 32 + wv * 4 + p4;
    short8 xbh[4], xbl[4];
    load_frags(xlf + (size_t)g * 2048, q, n16, xbh, xbl);
    epic_pass<true>(g, wv, q, n16, lane16, xbh, xbl, w1h_l, w1l_l, w2h_l, w2l_l,
                    gbias_s, l2b_s, outw_s, gbias_s /*dead*/,
                    const_cast<float*>(xlf), maskp, outp);
  }
}

extern "C" void kernel_launch(void* const* d_in, const int* in_sizes, int n_in,
                              void* d_out, int out_size, void* d_ws, size_t ws_size,
                              hipStream_t stream) {
  const float* x_local = (const float*)d_in[0];
  const float* context = (const float*)d_in[1];
  const float* mask = (const float*)d_in[2];
  const float* proj_lw = (const float*)d_in[3];
  const float* proj_lb = (const float*)d_in[4];
  const float* proj_g0w = (const float*)d_in[5];
  const float* proj_g0b = (const float*)d_in[6];
  const float* proj_g1w = (const float*)d_in[7];
  const float* proj_g1b = (const float*)d_in[8];
  const float* proj_g2w = (const float*)d_in[9];
  const float* proj_g2b = (const float*)d_in[10];
  const float* g1w = (const float*)d_in[11];
  const float* g1b = (const float*)d_in[12];
  const float* g2w = (const float*)d_in[13];
  const float* g2b = (const float*)d_in[14];
  const float* l1w = (const float*)d_in[15];
  const float* l1b = (const float*)d_in[16];
  const float* l2w = (const float*)d_in[17];
  const float* l2b = (const float*)d_in[18];
  const float* outw = (const float*)d_in[19];
  const float* outb = (const float*)d_in[20];
  float* out = (float*)d_out;

  char* ws = (char*)d_ws;
  float* xlf = (float*)ws;                                  // 67,108,864
  float* pP = (float*)(ws + 67108864);                      //  1,048,576
  float* cntp = (float*)(ws + 68157440);                    //      4,096
  float* cnt_g = (float*)(ws + 68161536);                   //         64
  float* xg_g = (float*)(ws + 68161600);                    //      7,168
  float* gbias_g = (float*)(ws + 68168768);                 //     49,152
  unsigned int* counters = (unsigned int*)(ws + 68217920);  //        448
  unsigned short* w1h = (unsigned short*)(ws + 68218368);   //    196,608
  unsigned short* w1l = (unsigned short*)(ws + 68414976);   //    196,608
  unsigned short* w2h = (unsigned short*)(ws + 68611584);   //    196,608
  unsigned short* w2l = (unsigned short*)(ws + 68808192);   //    196,608
  // end: 69,004,800 (< proven 70,018,304)

  prep_weights<<<384, 256, 0, stream>>>(l1w, l2w, w1h, w1l, w2h, w2l, counters);
  proj_local_kernel<<<1024, 256, 0, stream>>>(
      x_local, mask, proj_lw, proj_lb, xlf, pP, cntp, cnt_g, counters, context,
      proj_g0w, proj_g0b, proj_g1w, proj_g1b, proj_g2w, proj_g2b, xg_g,
      g1w, g1b, g2w, g2b, l1w, l1b, gbias_g);
  for (int i = 0; i < NB_; ++i) {
    const int j = i + 1;  // next block (tail target)
    const float* g1w_n = g1w + (size_t)j * 128 * 282;
    const float* g1b_n = g1b + j * 128;
    const float* g2w_n = g2w + j * 10 * 128;
    const float* g2b_n = g2b + j * 10;
    const float* l1w_n = l1w + (size_t)j * 128 * 154;
    const float* l1b_n = l1b + j * 128;
    const unsigned short* w1h_i = w1h + i * 16384;
    const unsigned short* w1l_i = w1l + i * 16384;
    const unsigned short* w2h_i = w2h + i * 16384;
    const unsigned short* w2l_i = w2l + i * 16384;
    if (i == NB_ - 1) {
      epic_last_kernel<<<256, 512, 0, stream>>>(
          xlf, gbias_g + (size_t)(i * 16) * 128, l2b + i * 128,
          w1h_i, w1l_i, w2h_i, w2l_i, mask, outw, outb, out);
    } else {
      epic_local_kernel<<<256, 1024, 0, stream>>>(
          xlf, pP, cnt_g, counters + (i + 1) * 16, gbias_g + (size_t)(i * 16) * 128,
          xg_g + (i + 1) * 16 * 16, xg_g + (i + 2) * 16 * 16,
          gbias_g + (size_t)((i + 1) * 16) * 128, context,
          g1w_n, g1b_n, g2w_n, g2b_n, l1w_n, l1b_n,
          l2b + i * 128, w1h_i, w1l_i, w2h_i, w2l_i, mask, out);
    }
  }
}

// Round 8
// 413.188 us; speedup vs baseline: 1.1322x; 1.0904x over previous
//
#include <hip/hip_runtime.h>
#include <hip/hip_bf16.h>

// EPiC network, round 19: tail restructure — prologue-tails, no winners.
// r18 post-mortem: prefetch neutral (falsified) -> tails are not cold-load
// bound; they are serial low-occupancy bubbles (proj Occ 8.4%: 16 WGs run the
// pool->MLP->gbias chain while the GPU idles; same at every epic_local end).
// r19: every dispatch computes ITS OWN layer's tail at START, redundantly in
// all WGs (deterministic FP; identical concurrent stores benign), overlapped
// with weight-staging DMA at full occupancy. gbias -> LDS directly. Winner/
// atomic machinery deleted (also removes the 20ms _ord-320 outlier risk class).
// Cross-dispatch dataflow via pP/cntp/xg_g with kernel-boundary visibility
// (NO spin barriers — unlike failed r15). Ping-pong pPe0/pPe1 pool buffers
// avoid same-dispatch read/write overlap. All GEMM/tail code verbatim r16/r18.

typedef __attribute__((ext_vector_type(8))) short short8;
typedef __attribute__((ext_vector_type(4))) float f32x4;

#define B_ 16
#define N_ 8192
#define DC_ 16
#define H_ 128
#define G_ 10
#define NB_ 6
#define NEG_ 0.01f

__device__ __forceinline__ float lrelu(float x) { return x > 0.f ? x : NEG_ * x; }

__device__ __forceinline__ unsigned short f2bf(float x) {
  union { float f; unsigned u; } v; v.f = x;
  return (unsigned short)((v.u + 0x7fffu + ((v.u >> 16) & 1u)) >> 16);  // RNE
}
__device__ __forceinline__ float bf2f(unsigned short u) {
  union { unsigned u; float f; } v; v.u = ((unsigned)u) << 16; return v.f;
}
// truncating hi (1 op) + RNE lo of residual; pair represents x to ~2^-17
__device__ __forceinline__ void split_bf(float x, unsigned short& h, unsigned short& l) {
  union { float f; unsigned u; } v; v.f = x;
  unsigned hu = v.u & 0xffff0000u;
  h = (unsigned short)(hu >> 16);
  union { unsigned u; float f; } hv; hv.u = hu;
  l = f2bf(x - hv.f);
}

__device__ __forceinline__ f32x4 mfma16(short8 a, short8 b, f32x4 c) {
  return __builtin_amdgcn_mfma_f32_16x16x32_bf16(a, b, c, 0, 0, 0);
}

__device__ __forceinline__ void make_frags(f32x4 v0, f32x4 v1, short8& bh, short8& bl) {
  unsigned short h, l;
#pragma unroll
  for (int j = 0; j < 4; ++j) {
    split_bf(v0[j], h, l);
    bh[j] = (short)h; bl[j] = (short)l;
  }
#pragma unroll
  for (int j = 0; j < 4; ++j) {
    split_bf(v1[j], h, l);
    bh[4 + j] = (short)h; bl[4 + j] = (short)l;
  }
}

// async 16B-per-lane global -> LDS copy (lane-contiguous DMA)
__device__ __forceinline__ void async_cp16(const void* g, void* l) {
  __builtin_amdgcn_global_load_lds(
      (const __attribute__((address_space(1))) void*)g,
      (__attribute__((address_space(3))) void*)l, 16, 0, 0);
}

// agent-scope write-through publication (no L2 flush)
__device__ __forceinline__ void agent_store(float* p, float v) {
  __hip_atomic_store(p, v, __ATOMIC_RELAXED, __HIP_MEMORY_SCOPE_AGENT);
}
__device__ __forceinline__ float agent_load(const float* p) {
  return __hip_atomic_load(p, __ATOMIC_RELAXED, __HIP_MEMORY_SCOPE_AGENT);
}

// ---- common tail: pool(NS slots) -> h_g -> xg residual -> folded gbias ----
// blockDim-agnostic: compute guarded, barriers unconditional. (verified)
template <int NS>
__device__ void epic_global_tail(
    int b, int tid, const float* __restrict__ pP, float cnt,
    const float* __restrict__ xg_cur, float* __restrict__ xg_next,
    const float* __restrict__ context,
    const float* __restrict__ g1w_n, const float* __restrict__ g1b_n,
    const float* __restrict__ g2w_n, const float* __restrict__ g2b_n,
    const float* __restrict__ l1w_n, const float* __restrict__ l1b_n,
    float* __restrict__ gbias_out, float* shx) {
  if (tid < 256) {
    const int f = tid & 127, kh = tid >> 7;
    const float* pr = pP + ((size_t)b * NS + kh * (NS / 2)) * 128 + f;
    float s = 0.f;
#pragma unroll 8
    for (int w = 0; w < NS / 2; ++w) s += agent_load(pr + w * 128);
    shx[tid] = s;
  }
  __syncthreads();
  if (tid < 128) {
    float s = shx[tid] + shx[tid + 128];
    shx[384 + tid] = s;
    shx[256 + tid] = s / cnt;
  }
  if (tid < G_) shx[512 + tid] = xg_cur[tid];
  if (tid >= 32 && tid < 32 + DC_) shx[522 + tid - 32] = context[b * DC_ + tid - 32];
  __syncthreads();
  if (tid < 256) {
    const int f = tid & 127, kh = tid >> 7;
    const float* wr = g1w_n + (size_t)f * 282 + kh * 142;
    const float* vp = shx + 256 + kh * 142;
    const int n2 = kh ? 70 : 71;
    float a = 0.f;
#pragma unroll 8
    for (int j = 0; j < n2; ++j) {
      float2 w2 = *(const float2*)(wr + 2 * j);
      a += w2.x * vp[2 * j] + w2.y * vp[2 * j + 1];
    }
    shx[tid] = a;  // writes 0..255; reads were 256..539 (disjoint)
  }
  __syncthreads();
  if (tid < 128) shx[544 + tid] = lrelu(shx[tid] + shx[tid + 128] + g1b_n[tid]);
  __syncthreads();
  if (tid < G_) {
    const float* wr = g2w_n + tid * 128;
    float a = g2b_n[tid] + shx[512 + tid];
#pragma unroll 8
    for (int j = 0; j < 32; ++j) {
      float4 w4 = *(const float4*)(wr + 4 * j);
      a += w4.x * shx[544 + 4 * j] + w4.y * shx[544 + 4 * j + 1] +
           w4.z * shx[544 + 4 * j + 2] + w4.w * shx[544 + 4 * j + 3];
    }
    float v = lrelu(a);
    shx[672 + tid] = v;
    xg_next[tid] = v;
  }
  __syncthreads();
  if (tid < 128) {
    const float* wr = l1w_n + tid * 154;
    float a = l1b_n[tid];
#pragma unroll
    for (int j = 0; j < G_; ++j) a += wr[128 + j] * shx[672 + j];
#pragma unroll
    for (int j = 0; j < DC_; ++j) a += wr[138 + j] * shx[522 + j];
    gbias_out[tid] = a;
  }
}

// ---- shared prologue: cnt + (FIRST: proj MLP -> xg_0) + this-layer tail ----
// gbias lands in LDS (gbias_s). Trailing barrier at call site.
template <bool FIRST, int NS>
__device__ void epic_prologue(
    int b, int tid, int layer,
    const float* __restrict__ pP_in, const float* __restrict__ cntp,
    const float* __restrict__ context, float* __restrict__ xg_g,
    const float* __restrict__ g1w_i, const float* __restrict__ g1b_i,
    const float* __restrict__ g2w_i, const float* __restrict__ g2b_i,
    const float* __restrict__ l1w_i, const float* __restrict__ l1b_i,
    const float* __restrict__ g0w, const float* __restrict__ g0b,
    const float* __restrict__ g1pw, const float* __restrict__ g1pb,
    const float* __restrict__ g2pw, const float* __restrict__ g2pb,
    float* gbias_s, float* shx) {
  // cnt from proj's per-WG partials (verified pattern)
  if (tid < 64) shx[688 + tid] = agent_load(&cntp[b * 64 + tid]);
  __syncthreads();
  if (tid == 0) {
    float c = 0.f;
#pragma unroll
    for (int w = 0; w < 64; ++w) c += shx[688 + w];
    shx[752] = c;
  }
  __syncthreads();
  const float cnt = shx[752];

  if (FIRST) {
    // ---- proj global MLP: pool(128) -> g0 -> g1p -> g2p -> xg_0 ----
    if (tid < 256) {
      const int f = tid & 127, kh = tid >> 7;
      const float* pr = pP_in + ((size_t)b * 128 + kh * 64) * 128 + f;
      float s = 0.f;
#pragma unroll 8
      for (int w = 0; w < 64; ++w) s += agent_load(pr + w * 128);
      shx[tid] = s;
    }
    __syncthreads();
    if (tid < 128) {
      float s = shx[tid] + shx[tid + 128];
      shx[384 + tid] = s;
      shx[256 + tid] = s / cnt;
    }
    if (tid < DC_) shx[512 + tid] = context[b * DC_ + tid];
    __syncthreads();
    {
      float a = 0.f;
      if (tid < 256) {
        const int f = tid & 127, kh = tid >> 7;
        const float* wr = g0w + (size_t)f * 272 + kh * 136;
        const float* vp = shx + 256 + kh * 136;
#pragma unroll 8
        for (int j = 0; j < 34; ++j) {
          float4 w4 = *(const float4*)(wr + 4 * j);
          a += w4.x * vp[4 * j] + w4.y * vp[4 * j + 1] + w4.z * vp[4 * j + 2] + w4.w * vp[4 * j + 3];
        }
      }
      __syncthreads();
      if (tid < 256) shx[tid] = a;
    }
    __syncthreads();
    if (tid < 128) shx[544 + tid] = lrelu(shx[tid] + shx[tid + 128] + g0b[tid]);
    __syncthreads();
    {
      float a = 0.f;
      if (tid < 256) {
        const int f = tid & 127, kh = tid >> 7;
        const float* wr = g1pw + (size_t)f * 128 + kh * 64;
        const float* vp = shx + 544 + kh * 64;
#pragma unroll 8
        for (int j = 0; j < 16; ++j) {
          float4 w4 = *(const float4*)(wr + 4 * j);
          a += w4.x * vp[4 * j] + w4.y * vp[4 * j + 1] + w4.z * vp[4 * j + 2] + w4.w * vp[4 * j + 3];
        }
      }
      __syncthreads();
      if (tid < 256) shx[tid] = a;
    }
    __syncthreads();
    if (tid < 128) shx[544 + tid] = lrelu(shx[tid] + shx[tid + 128] + g1pb[tid]);
    __syncthreads();
    if (tid < G_) {
      const float* wr = g2pw + tid * 128;
      float a = g2pb[tid];
#pragma unroll 8
      for (int j = 0; j < 32; ++j) {
        float4 w4 = *(const float4*)(wr + 4 * j);
        a += w4.x * shx[544 + 4 * j] + w4.y * shx[544 + 4 * j + 1] +
             w4.z * shx[544 + 4 * j + 2] + w4.w * shx[544 + 4 * j + 3];
      }
      xg_g[(0 * 16 + b) * 16 + tid] = lrelu(a);  // identical across batch WGs
    }
    __syncthreads();
  }
  // ---- this layer's tail: gbias_i -> LDS, xg_{i+1} -> global slot ----
  epic_global_tail<NS>(b, tid, pP_in, cnt,
                       xg_g + ((size_t)layer * 16 + b) * 16,
                       xg_g + ((size_t)(layer + 1) * 16 + b) * 16, context,
                       g1w_i, g1b_i, g2w_i, g2b_i, l1w_i, l1b_i, gbias_s, shx);
}

// ---------------- weight prep: split + frag-order swizzle ----------------
__global__ __launch_bounds__(256) void prep_weights(
    const float* __restrict__ l1w, const float* __restrict__ l2w,
    unsigned short* __restrict__ w1h, unsigned short* __restrict__ w1l,
    unsigned short* __restrict__ w2h, unsigned short* __restrict__ w2l) {
  int idx = blockIdx.x * 256 + threadIdx.x;
  const int total = NB_ * H_ * H_;
  if (idx < total) {
    int i = idx / (H_ * H_), rem = idx % (H_ * H_);
    int F = rem / H_, k = rem % H_;
    int ks = k >> 5, c = k & 31;
    int mt2 = F >> 4, r2 = F & 15;
    int mt1 = ((F >> 5) << 1) | ((F >> 2) & 1);
    int r1 = (((F >> 3) & 3) << 2) | (F & 3);
    int off1 = i * 16384 + (mt1 * 4 + ks) * 512 + ((c >> 3) * 16 + r1) * 8 + (c & 7);
    int off2 = i * 16384 + (mt2 * 4 + ks) * 512 + ((c >> 3) * 16 + r2) * 8 + (c & 7);
    unsigned short h, l;
    split_bf(l1w[(i * H_ + F) * 154 + k], h, l);
    w1h[off1] = h; w1l[off1] = l;
    split_bf(l2w[(i * H_ + F) * H_ + k], h, l);
    w2h[off2] = h; w2l[off2] = l;
  }
}

// ---------------- projection local (pure local now: xlf + pP + cntp) ----------
__global__ __launch_bounds__(256, 2) void proj_local_kernel(
    const float* __restrict__ xloc, const float* __restrict__ maskp,
    const float* __restrict__ plw, const float* __restrict__ plb,
    float* __restrict__ xlf, float* __restrict__ pP,
    float* __restrict__ cntp) {
  __shared__ float wq[H_][4];
  __shared__ float wsum[512];
  __shared__ float cw[4];
  const int tid = threadIdx.x, bid = blockIdx.x;
  const int wv = tid >> 6, lane = tid & 63;
  const int q = lane >> 4, n16 = lane & 15;
  if (tid < H_) {
    wq[tid][0] = plw[tid * 3 + 0];
    wq[tid][1] = plw[tid * 3 + 1];
    wq[tid][2] = plw[tid * 3 + 2];
    wq[tid][3] = plb[tid];
  }
  __syncthreads();
  const int t = bid * 4 + wv;            // 32-pt tile index
  const int p0 = t * 32;
  const int pa = p0 + n16, pb = p0 + 16 + n16;
  const float xa0 = xloc[pa * 3], xa1 = xloc[pa * 3 + 1], xa2 = xloc[pa * 3 + 2];
  const float xb0 = xloc[pb * 3], xb1 = xloc[pb * 3 + 1], xb2 = xloc[pb * 3 + 2];
  const float m0 = maskp[pa], m1 = maskp[pb];
  float* ga = xlf + (size_t)(2 * t) * 2048;
  float* gb = ga + 2048;
#pragma unroll
  for (int ms = 0; ms < 8; ++ms) {
    f32x4 v0, v1;
#pragma unroll
    for (int r = 0; r < 4; ++r) {
      const int F = ms * 16 + q * 4 + r;
      float4 w4 = *(const float4*)wq[F];
      v0[r] = lrelu(w4.x * xa0 + w4.y * xa1 + w4.z * xa2 + w4.w) * m0;
      v1[r] = lrelu(w4.x * xb0 + w4.y * xb1 + w4.z * xb2 + w4.w) * m1;
    }
    *(f32x4*)(ga + ms * 256 + (q * 16 + n16) * 4) = v0;
    *(f32x4*)(gb + ms * 256 + (q * 16 + n16) * 4) = v1;
    f32x4 s = v0 + v1;
#pragma unroll
    for (int r = 0; r < 4; ++r) {
      float sv = s[r];
      sv += __shfl_xor(sv, 1, 64);
      sv += __shfl_xor(sv, 2, 64);
      sv += __shfl_xor(sv, 4, 64);
      sv += __shfl_xor(sv, 8, 64);
      s[r] = sv;
    }
    if (n16 == 0) *(f32x4*)&wsum[wv * 128 + ms * 16 + q * 4] = s;
  }
  {
    float c = (q == 0) ? (m0 + m1) : 0.f;
    c += __shfl_xor(c, 1, 64);
    c += __shfl_xor(c, 2, 64);
    c += __shfl_xor(c, 4, 64);
    c += __shfl_xor(c, 8, 64);
    if (lane == 0) cw[wv] = c;
  }
  __syncthreads();
  // two 64-pt slots per WG -> 128 slots per batch
  if (tid < 128) {
    agent_store(&pP[(size_t)(2 * bid) * 128 + tid], wsum[tid] + wsum[128 + tid]);
    agent_store(&pP[(size_t)(2 * bid + 1) * 128 + tid], wsum[256 + tid] + wsum[384 + tid]);
  }
  if (tid == 0) agent_store(&cntp[bid], cw[0] + cw[1] + cw[2] + cw[3]);
}

// ---- per-group x B-frag load (B-layout, verified) ----
__device__ __forceinline__ void load_frags(const float* base_g, int q, int n16,
                                           short8* xbh, short8* xbl) {
#pragma unroll
  for (int ks = 0; ks < 4; ++ks) {
    const float* pb = base_g + (2 * ks + (q >> 1)) * 256 + ((q & 1) * 32 + n16) * 4;
    f32x4 v0 = *(const f32x4*)pb;
    f32x4 v1 = *(const f32x4*)(pb + 64);
    make_frags(v0, v1, xbh[ks], xbl[ks]);
  }
}

// ---- one group's K-loop + epilogue (verified r16/r18) ----
template <bool LAST>
__device__ __forceinline__ void epic_pass(
    int g, int wv, int q, int n16, int lane16,
    const short8* xbh, const short8* xbl,
    const unsigned short* w1h_l, const unsigned short* w1l_l,
    const unsigned short* w2h_l, const unsigned short* w2l_l,
    const float* gbias_s, const float* l2b_s, const float* outw_s,
    float* wsum, float* __restrict__ xlf, const float* __restrict__ maskp,
    float* __restrict__ outp) {
  f32x4 acc2[8];
#pragma unroll
  for (int ms = 0; ms < 8; ++ms) acc2[ms] = (f32x4){0.f, 0.f, 0.f, 0.f};

#pragma unroll 1
  for (int ko = 0; ko < 4; ++ko) {
    f32x4 acc[2][2];
#pragma unroll
    for (int t = 0; t < 2; ++t)
#pragma unroll
      for (int kc = 0; kc < 2; ++kc) acc[t][kc] = (f32x4){0.f, 0.f, 0.f, 0.f};
#pragma unroll
    for (int t = 0; t < 2; ++t) {
#pragma unroll
      for (int kc = 0; kc < 2; ++kc) {  // ks chunks of 2 (16 transient regs)
        short8 a1h[2], a1l[2];
#pragma unroll
        for (int u = 0; u < 2; ++u) {
          const int off = ((ko * 2 + t) * 4 + kc * 2 + u) * 512 + lane16;
          a1h[u] = *(const short8*)(w1h_l + off);
          a1l[u] = *(const short8*)(w1l_l + off);
        }
#pragma unroll
        for (int u = 0; u < 2; ++u) {
          const int ks = kc * 2 + u;
          acc[t][kc] = mfma16(a1h[u], xbh[ks], acc[t][kc]);
          acc[t][kc] = mfma16(a1l[u], xbh[ks], acc[t][kc]);
          acc[t][kc] = mfma16(a1h[u], xbl[ks], acc[t][kc]);
        }
      }
    }
    f32x4 gb0 = *(const f32x4*)&gbias_s[ko * 32 + q * 8];
    f32x4 gb1 = *(const f32x4*)&gbias_s[ko * 32 + q * 8 + 4];
    f32x4 hv0, hv1;
#pragma unroll
    for (int r = 0; r < 4; ++r) {
      hv0[r] = lrelu(acc[0][0][r] + acc[0][1][r] + gb0[r]);
      hv1[r] = lrelu(acc[1][0][r] + acc[1][1][r] + gb1[r]);
    }
    short8 b2h, b2l;
    make_frags(hv0, hv1, b2h, b2l);
#pragma unroll
    for (int mc = 0; mc < 4; ++mc) {
      short8 a2h[2], a2l[2];
#pragma unroll
      for (int u = 0; u < 2; ++u) {
        const int off = ((mc * 2 + u) * 4 + ko) * 512 + lane16;
        a2h[u] = *(const short8*)(w2h_l + off);
        a2l[u] = *(const short8*)(w2l_l + off);
      }
#pragma unroll
      for (int u = 0; u < 2; ++u) {
        const int ms = mc * 2 + u;
        acc2[ms] = mfma16(a2h[u], b2h, acc2[ms]);
        acc2[ms] = mfma16(a2l[u], b2h, acc2[ms]);
        acc2[ms] = mfma16(a2h[u], b2l, acc2[ms]);
      }
    }
  }

  const float mk = maskp[g * 16 + n16];
  float po[3];
  if (LAST) po[0] = po[1] = po[2] = 0.f;
  float* base_w = xlf + (size_t)g * 2048;
#pragma unroll
  for (int ms = 0; ms < 8; ++ms) {
    f32x4 lb4 = *(const f32x4*)&l2b_s[ms * 16 + q * 4];
    float* xo = base_w + ms * 256 + (q * 16 + n16) * 4;
    f32x4 old = *(const f32x4*)xo;
    f32x4 v;
#pragma unroll
    for (int r = 0; r < 4; ++r) v[r] = lrelu(acc2[ms][r] + lb4[r] + old[r]) * mk;
    if (!LAST) {
      *(f32x4*)xo = v;
      f32x4 sr;
#pragma unroll
      for (int r = 0; r < 4; ++r) {
        float s = v[r];
        s += __shfl_xor(s, 1, 64);
        s += __shfl_xor(s, 2, 64);
        s += __shfl_xor(s, 4, 64);
        s += __shfl_xor(s, 8, 64);
        sr[r] = s;
      }
      if (n16 == 0) *(f32x4*)&wsum[wv * 128 + ms * 16 + q * 4] = sr;
    } else {
      f32x4 w0 = *(const f32x4*)&outw_s[0 * 128 + ms * 16 + q * 4];
      f32x4 w1 = *(const f32x4*)&outw_s[1 * 128 + ms * 16 + q * 4];
      f32x4 w2 = *(const f32x4*)&outw_s[2 * 128 + ms * 16 + q * 4];
#pragma unroll
      for (int r = 0; r < 4; ++r) {
        po[0] += v[r] * w0[r];
        po[1] += v[r] * w1[r];
        po[2] += v[r] * w2[r];
      }
    }
  }
  if (LAST) {
#pragma unroll
    for (int o = 0; o < 3; ++o) {
      float s = po[o];
      s += __shfl_xor(s, 16, 64);
      s += __shfl_xor(s, 32, 64);
      po[o] = s;
    }
    if (q == 0) {
      const int p = g * 16 + n16;
#pragma unroll
      for (int o = 0; o < 3; ++o)
        outp[(size_t)p * 3 + o] = (po[o] + outw_s[384 + o]) * mk;
    }
  }
}

// ---------------- epic local (layers 0..4): prologue-tail + 2 passes ----------
template <bool FIRST>
__global__ __launch_bounds__(1024) void epic_local_kernel(
    float* __restrict__ xlf,
    const float* __restrict__ pP_in, float* __restrict__ pP_out,
    const float* __restrict__ cntp, const float* __restrict__ context,
    float* __restrict__ xg_g, int layer,
    const float* __restrict__ g1w_i, const float* __restrict__ g1b_i,
    const float* __restrict__ g2w_i, const float* __restrict__ g2b_i,
    const float* __restrict__ l1w_i, const float* __restrict__ l1b_i,
    const float* __restrict__ g0w, const float* __restrict__ g0b,
    const float* __restrict__ g1pw, const float* __restrict__ g1pb,
    const float* __restrict__ g2pw, const float* __restrict__ g2pb,
    const float* __restrict__ l2b,
    const unsigned short* __restrict__ w1h, const unsigned short* __restrict__ w1l,
    const unsigned short* __restrict__ w2h, const unsigned short* __restrict__ w2l,
    const float* __restrict__ maskp) {
  __shared__ unsigned short wbuf[65536];  // 128 KB: w1h|w1l|w2h|w2l
  __shared__ float shx[768];
  __shared__ float gbias_s[128];
  __shared__ float l2b_s[128];
  __shared__ float wsum[2048];
  const int tid = threadIdx.x, bid = blockIdx.x;
  const int b = bid >> 4;   // 16 WGs per batch
  const int wv = tid >> 6, lane = tid & 63;
  const int q = lane >> 4, n16 = lane & 15;

  // ---- stage weights (issue first; drained at first prologue barrier) ----
  {
    const unsigned short* src =
        (wv < 4) ? w1h : (wv < 8) ? w1l : (wv < 12) ? w2h : w2l;
    const char* s8 = (const char*)(src + (wv & 3) * 4096) + lane * 16;
    char* d8 = (char*)wbuf + wv * 8192;
#pragma unroll
    for (int j = 0; j < 8; ++j) async_cp16(s8 + j * 1024, d8 + j * 1024);
  }
  if (tid < 128) l2b_s[tid] = l2b[tid];

  // ---- prologue: this layer's tail, all WGs, gbias -> LDS ----
  epic_prologue<FIRST, FIRST ? 128 : 32>(
      b, tid, layer, pP_in, cntp, context, xg_g,
      g1w_i, g1b_i, g2w_i, g2b_i, l1w_i, l1b_i,
      g0w, g0b, g1pw, g1pb, g2pw, g2pb, gbias_s, shx);
  __syncthreads();  // gbias_s ready

  const int gA = bid * 32 + wv;
  const int gB = bid * 32 + 16 + wv;
  short8 xbh[4], xbl[4];
  load_frags(xlf + (size_t)gA * 2048, q, n16, xbh, xbl);

  const unsigned short* w1h_l = wbuf;
  const unsigned short* w1l_l = wbuf + 16384;
  const unsigned short* w2h_l = wbuf + 32768;
  const unsigned short* w2l_l = wbuf + 49152;
  const int lane16 = lane * 8;

  // ---- pass A ----
  epic_pass<false>(gA, wv, q, n16, lane16, xbh, xbl, w1h_l, w1l_l, w2h_l, w2l_l,
                   gbias_s, l2b_s, nullptr, wsum, xlf, maskp, nullptr);
  __syncthreads();
  if (tid < 128) {
    float s = 0.f;
#pragma unroll
    for (int w = 0; w < 16; ++w) s += wsum[w * 128 + tid];
    agent_store(&pP_out[(size_t)(bid * 2) * 128 + tid], s);
  }
  __syncthreads();  // protect wsum before pass B overwrites

  // ---- pass B ----
  load_frags(xlf + (size_t)gB * 2048, q, n16, xbh, xbl);
  epic_pass<false>(gB, wv, q, n16, lane16, xbh, xbl, w1h_l, w1l_l, w2h_l, w2l_l,
                   gbias_s, l2b_s, nullptr, wsum, xlf, maskp, nullptr);
  __syncthreads();
  if (tid < 128) {
    float s = 0.f;
#pragma unroll
    for (int w = 0; w < 16; ++w) s += wsum[w * 128 + tid];
    agent_store(&pP_out[(size_t)(bid * 2 + 1) * 128 + tid], s);
  }
}

// ---------------- LAST layer: prologue-tail + head, 512 thr ----------------
__global__ __launch_bounds__(512, 2) void epic_last_kernel(
    const float* __restrict__ xlf,
    const float* __restrict__ pP_in, const float* __restrict__ cntp,
    const float* __restrict__ context, float* __restrict__ xg_g,
    const float* __restrict__ g1w_i, const float* __restrict__ g1b_i,
    const float* __restrict__ g2w_i, const float* __restrict__ g2b_i,
    const float* __restrict__ l1w_i, const float* __restrict__ l1b_i,
    const float* __restrict__ l2b,
    const unsigned short* __restrict__ w1h, const unsigned short* __restrict__ w1l,
    const unsigned short* __restrict__ w2h, const unsigned short* __restrict__ w2l,
    const float* __restrict__ maskp,
    const float* __restrict__ outw, const float* __restrict__ outb,
    float* __restrict__ outp) {
  __shared__ unsigned short wbuf[65536];  // 128 KB
  __shared__ float shx[768];
  __shared__ float gbias_s[128];
  __shared__ float l2b_s[128];
  __shared__ float outw_s[392];
  const int tid = threadIdx.x, bid = blockIdx.x;
  const int b = bid >> 4;
  const int wv = tid >> 6, lane = tid & 63;
  const int q = lane >> 4, n16 = lane & 15;
  const int lane16 = lane * 8;

  {
    const unsigned short* src =
        (wv < 2) ? w1h : (wv < 4) ? w1l : (wv < 6) ? w2h : w2l;
    const char* s8 = (const char*)(src + (wv & 1) * 8192) + lane * 16;
    char* d8 = (char*)wbuf + wv * 16384;
#pragma unroll
    for (int j = 0; j < 16; ++j) async_cp16(s8 + j * 1024, d8 + j * 1024);
  }
  if (tid < 128) l2b_s[tid] = l2b[tid];
  if (tid < 384) outw_s[tid] = outw[tid];
  if (tid >= 384 && tid < 387) outw_s[tid] = outb[tid - 384];

  // ---- prologue: layer-5 tail (gbias_5 -> LDS) ----
  epic_prologue<false, 32>(
      b, tid, 5, pP_in, cntp, context, xg_g,
      g1w_i, g1b_i, g2w_i, g2b_i, l1w_i, l1b_i,
      nullptr, nullptr, nullptr, nullptr, nullptr, nullptr, gbias_s, shx);
  __syncthreads();  // gbias_s ready; staging drained long before

  const unsigned short* w1h_l = wbuf;
  const unsigned short* w1l_l = wbuf + 16384;
  const unsigned short* w2h_l = wbuf + 32768;
  const unsigned short* w2l_l = wbuf + 49152;

#pragma unroll 1
  for (int p4 = 0; p4 < 4; ++p4) {
    const int g = bid * 32 + wv * 4 + p4;
    short8 xbh[4], xbl[4];
    load_frags(xlf + (size_t)g * 2048, q, n16, xbh, xbl);
    epic_pass<true>(g, wv, q, n16, lane16, xbh, xbl, w1h_l, w1l_l, w2h_l, w2l_l,
                    gbias_s, l2b_s, outw_s, gbias_s /*dead*/,
                    const_cast<float*>(xlf), maskp, outp);
  }
}

extern "C" void kernel_launch(void* const* d_in, const int* in_sizes, int n_in,
                              void* d_out, int out_size, void* d_ws, size_t ws_size,
                              hipStream_t stream) {
  const float* x_local = (const float*)d_in[0];
  const float* context = (const float*)d_in[1];
  const float* mask = (const float*)d_in[2];
  const float* proj_lw = (const float*)d_in[3];
  const float* proj_lb = (const float*)d_in[4];
  const float* proj_g0w = (const float*)d_in[5];
  const float* proj_g0b = (const float*)d_in[6];
  const float* proj_g1w = (const float*)d_in[7];
  const float* proj_g1b = (const float*)d_in[8];
  const float* proj_g2w = (const float*)d_in[9];
  const float* proj_g2b = (const float*)d_in[10];
  const float* g1w = (const float*)d_in[11];
  const float* g1b = (const float*)d_in[12];
  const float* g2w = (const float*)d_in[13];
  const float* g2b = (const float*)d_in[14];
  const float* l1w = (const float*)d_in[15];
  const float* l1b = (const float*)d_in[16];
  const float* l2w = (const float*)d_in[17];
  const float* l2b = (const float*)d_in[18];
  const float* outw = (const float*)d_in[19];
  const float* outb = (const float*)d_in[20];
  float* out = (float*)d_out;

  char* ws = (char*)d_ws;
  float* xlf = (float*)ws;                                  // 67,108,864
  float* pP = (float*)(ws + 67108864);                      //  1,048,576 (proj, 128 slots/batch)
  float* cntp = (float*)(ws + 68157440);                    //      4,096
  float* xg_g = (float*)(ws + 68161600);                    //      7,168 (7 slots x 16 batches x 16)
  unsigned short* w1h = (unsigned short*)(ws + 68218368);   //    196,608
  unsigned short* w1l = (unsigned short*)(ws + 68414976);   //    196,608
  unsigned short* w2h = (unsigned short*)(ws + 68611584);   //    196,608
  unsigned short* w2l = (unsigned short*)(ws + 68808192);   //    196,608
  float* pPe0 = (float*)(ws + 69004800);                    //    262,144 (epic pool ping)
  float* pPe1 = (float*)(ws + 69266944);                    //    262,144 (epic pool pong)
  // end: 69,529,088 (< proven 70,018,304)

  prep_weights<<<384, 256, 0, stream>>>(l1w, l2w, w1h, w1l, w2h, w2l);
  proj_local_kernel<<<1024, 256, 0, stream>>>(
      x_local, mask, proj_lw, proj_lb, xlf, pP, cntp);
  for (int i = 0; i < NB_ - 1; ++i) {  // layers 0..4
    const float* pP_in = (i == 0) ? pP : ((i & 1) ? pPe1 : pPe0);
    float* pP_out = ((i + 1) & 1) ? pPe1 : pPe0;
    const float* g1w_i = g1w + (size_t)i * 128 * 282;
    const float* g1b_i = g1b + i * 128;
    const float* g2w_i = g2w + (size_t)i * 10 * 128;
    const float* g2b_i = g2b + i * 10;
    const float* l1w_i = l1w + (size_t)i * 128 * 154;
    const float* l1b_i = l1b + i * 128;
    const unsigned short* w1h_i = w1h + i * 16384;
    const unsigned short* w1l_i = w1l + i * 16384;
    const unsigned short* w2h_i = w2h + i * 16384;
    const unsigned short* w2l_i = w2l + i * 16384;
    if (i == 0) {
      epic_local_kernel<true><<<256, 1024, 0, stream>>>(
          xlf, pP_in, pP_out, cntp, context, xg_g, i,
          g1w_i, g1b_i, g2w_i, g2b_i, l1w_i, l1b_i,
          proj_g0w, proj_g0b, proj_g1w, proj_g1b, proj_g2w, proj_g2b,
          l2b + i * 128, w1h_i, w1l_i, w2h_i, w2l_i, mask);
    } else {
      epic_local_kernel<false><<<256, 1024, 0, stream>>>(
          xlf, pP_in, pP_out, cntp, context, xg_g, i,
          g1w_i, g1b_i, g2w_i, g2b_i, l1w_i, l1b_i,
          nullptr, nullptr, nullptr, nullptr, nullptr, nullptr,
          l2b + i * 128, w1h_i, w1l_i, w2h_i, w2l_i, mask);
    }
  }
  {
    const int i = NB_ - 1;  // layer 5
    epic_last_kernel<<<256, 512, 0, stream>>>(
        xlf, pPe1 /* written by layer 4 */, cntp, context, xg_g,
        g1w + (size_t)i * 128 * 282, g1b + i * 128,
        g2w + (size_t)i * 10 * 128, g2b + i * 10,
        l1w + (size_t)i * 128 * 154, l1b + i * 128,
        l2b + i * 128, w1h + i * 16384, w1l + i * 16384,
        w2h + i * 16384, w2l + i * 16384, mask, outw, outb, out);
  }
}